// Round 5
// baseline (4056.509 us; speedup 1.0000x reference)
//
#include <hip/hip_runtime.h>
#include <hip/hip_bf16.h>
#include <math.h>

#define NR 8192
#define DD 1024

typedef __attribute__((ext_vector_type(8))) short bf16x8;
typedef __attribute__((ext_vector_type(4))) float f32x4;

struct u16x4 { unsigned short x, y, z, w; };

__device__ __forceinline__ unsigned short f2bf(float v) {
    __hip_bfloat16 h = __float2bfloat16(v);
    return *(unsigned short*)&h;
}
__device__ __forceinline__ float bf2f(unsigned short u) {
    __hip_bfloat16 h = *(__hip_bfloat16*)&u;
    return __bfloat162float(h);
}

// ---------------------------------------------------------------------------
// Projection GEMM (fp32, known-good).
// MODE 0: pack per-row records [hi(2048B)|lo(2048B)] into qpack (d_out).
// MODE 1: write khi/klo bf16 arrays (ws).
// ---------------------------------------------------------------------------
template <int MODE>
__global__ __launch_bounds__(256) void proj_gemm(const float* __restrict__ X,
                                                 const float* __restrict__ W,
                                                 char* qpack,
                                                 unsigned short* khi,
                                                 unsigned short* klo) {
    __shared__ float As[16][64];
    __shared__ float Bs[16][64];

    const int tid = threadIdx.x;
    const int tx = tid & 15;
    const int ty = tid >> 4;
    const int m0 = blockIdx.y * 64;
    const int n0 = blockIdx.x * 64;

    const int lm  = tid >> 2;
    const int lk4 = (tid & 3) * 4;
    const int bk  = tid >> 4;
    const int bn4 = (tid & 15) * 4;

    float acc[4][4] = {};

    for (int kb = 0; kb < DD; kb += 16) {
        float4 av = *(const float4*)(X + (size_t)(m0 + lm) * DD + kb + lk4);
        As[lk4 + 0][lm] = av.x;
        As[lk4 + 1][lm] = av.y;
        As[lk4 + 2][lm] = av.z;
        As[lk4 + 3][lm] = av.w;
        *(float4*)&Bs[bk][bn4] =
            *(const float4*)(W + (size_t)(kb + bk) * DD + n0 + bn4);
        __syncthreads();
#pragma unroll
        for (int k = 0; k < 16; ++k) {
            float4 a = *(const float4*)&As[k][ty * 4];
            float4 b = *(const float4*)&Bs[k][tx * 4];
            float aa[4] = {a.x, a.y, a.z, a.w};
            float bb[4] = {b.x, b.y, b.z, b.w};
#pragma unroll
            for (int i = 0; i < 4; ++i)
#pragma unroll
                for (int j = 0; j < 4; ++j) acc[i][j] += aa[i] * bb[j];
        }
        __syncthreads();
    }
#pragma unroll
    for (int i = 0; i < 4; ++i) {
        int row = m0 + ty * 4 + i;
        int col = n0 + tx * 4;
        u16x4 hi, lo;
        float v0 = acc[i][0], v1 = acc[i][1], v2 = acc[i][2], v3 = acc[i][3];
        hi.x = f2bf(v0); lo.x = f2bf(v0 - bf2f(hi.x));
        hi.y = f2bf(v1); lo.y = f2bf(v1 - bf2f(hi.y));
        hi.z = f2bf(v2); lo.z = f2bf(v2 - bf2f(hi.z));
        hi.w = f2bf(v3); lo.w = f2bf(v3 - bf2f(hi.w));
        if (MODE == 0) {
            *(u16x4*)(qpack + (size_t)row * 4096 + col * 2)        = hi;
            *(u16x4*)(qpack + (size_t)row * 4096 + 2048 + col * 2) = lo;
        } else {
            *(u16x4*)(khi + (size_t)row * 1024 + col) = hi;
            *(u16x4*)(klo + (size_t)row * 1024 + col) = lo;
        }
    }
}

// ---------------------------------------------------------------------------
// X^T bf16: XT[1024][8192] = bf16(X)^T  (PV B-operand layout)
// ---------------------------------------------------------------------------
__global__ __launch_bounds__(256) void prep_xt(const float* __restrict__ X,
                                               unsigned short* __restrict__ XT) {
    __shared__ float t[64][65];
    const int r0 = blockIdx.x * 64;
    const int c0 = blockIdx.y * 64;
    const int tid = threadIdx.x;
    const int tr = tid >> 6;
    const int tc = tid & 63;
#pragma unroll
    for (int rep = 0; rep < 16; ++rep) {
        int r = rep * 4 + tr;
        t[r][tc] = X[(size_t)(r0 + r) * DD + c0 + tc];
    }
    __syncthreads();
#pragma unroll
    for (int rep = 0; rep < 16; ++rep) {
        int c = rep * 4 + tr;
        XT[(size_t)(c0 + c) * NR + r0 + tc] = f2bf(t[tc][c]);
    }
}

// ---------------------------------------------------------------------------
// Flash attention v4: BM=64, BN=256, 512 thr = 8 waves (1x8).
// KV-split 4 (grid 512) so 68 KB LDS -> 2 blocks/CU -> 4 waves/SIMD (TLP).
// Direct global loads for K / XT fragments (flash2 style); Q chunked 128 cols.
// ---------------------------------------------------------------------------
template <bool SPLIT>
__global__ __launch_bounds__(512, 4) void flash4(
        const char* __restrict__ qpk,
        const unsigned short* __restrict__ Khi,
        const unsigned short* __restrict__ Klo,
        const unsigned short* __restrict__ XT,
        float* __restrict__ outp,
        unsigned short* __restrict__ On,
        float* __restrict__ mlbuf) {
    __shared__ __align__(128) char qlds[32768];   // Q chunk: hi[64][256B] | lo
    __shared__ __align__(128) char plds[32768];   // P: [64][512B] bf16, swizzled
    __shared__ __align__(16) float smaxf[64 * 8];
    __shared__ __align__(16) float ssumf[64 * 8];

    const int tid = threadIdx.x;
    const int l   = tid & 63;
    const int w   = tid >> 6;
    const int l15 = l & 15;
    const int lk  = l >> 4;
    const int swzA = l15 & 7;

    int qb, sp;
    if (SPLIT) { qb = blockIdx.x >> 2; sp = blockIdx.x & 3; }
    else       { qb = blockIdx.x;      sp = 0; }
    const int q0  = qb * 64;
    const int kv0 = SPLIT ? sp * (NR / 4) : 0;
    const int kv1 = SPLIT ? kv0 + (NR / 4) : NR;

    f32x4 o[4][8];
    float m_run[4][4], l_run[4][4];
#pragma unroll
    for (int mr = 0; mr < 4; ++mr) {
#pragma unroll
        for (int nf = 0; nf < 8; ++nf) o[mr][nf] = f32x4{0.f, 0.f, 0.f, 0.f};
#pragma unroll
        for (int g = 0; g < 4; ++g) { m_run[mr][g] = -3.0e38f; l_run[mr][g] = 0.f; }
    }

    for (int k0 = kv0; k0 < kv1; k0 += 256) {
        f32x4 acc[4][2];
#pragma unroll
        for (int mr = 0; mr < 4; ++mr)
#pragma unroll
            for (int nf = 0; nf < 2; ++nf) acc[mr][nf] = f32x4{0.f, 0.f, 0.f, 0.f};

        // ---- S = Q.K^T over D in 128-col chunks ----
        for (int c = 0; c < 8; ++c) {
            __syncthreads();   // prior chunk's qlds reads done
            // stage Q chunk hi/lo: 2048 16B-slots / 512 thr = 4 each
#pragma unroll
            for (int rep = 0; rep < 4; ++rep) {
                int s   = rep * 512 + tid;
                int arr = s >> 10;            // 0 hi, 1 lo
                int r   = (s >> 4) & 63;
                int j   = s & 15;
                bf16x8 v = *(const bf16x8*)(qpk + (size_t)(q0 + r) * 4096 +
                                            arr * 2048 + c * 256 + j * 16);
                *(bf16x8*)&qlds[arr * 16384 + r * 256 + ((j ^ (r & 7)) << 4)] = v;
            }
            __syncthreads();

#pragma unroll
            for (int ks = 0; ks < 4; ++ks) {
                bf16x8 bh[2], bl[2];
#pragma unroll
                for (int nf = 0; nf < 2; ++nf) {
                    size_t off = (size_t)(k0 + w * 32 + nf * 16 + l15) * 1024 +
                                 c * 128 + ks * 32 + lk * 8;
                    bh[nf] = *(const bf16x8*)(Khi + off);
                    bl[nf] = *(const bf16x8*)(Klo + off);
                }
                bf16x8 ah[4], al[4];
#pragma unroll
                for (int mr = 0; mr < 4; ++mr) {
                    int off = (mr * 16 + l15) * 256 + (((ks * 4 + lk) ^ swzA) << 4);
                    ah[mr] = *(const bf16x8*)&qlds[off];
                    al[mr] = *(const bf16x8*)&qlds[16384 + off];
                }
                __builtin_amdgcn_s_setprio(1);
#pragma unroll
                for (int mr = 0; mr < 4; ++mr)
#pragma unroll
                    for (int nf = 0; nf < 2; ++nf) {
                        acc[mr][nf] = __builtin_amdgcn_mfma_f32_16x16x32_bf16(ah[mr], bh[nf], acc[mr][nf], 0, 0, 0);
                        acc[mr][nf] = __builtin_amdgcn_mfma_f32_16x16x32_bf16(al[mr], bh[nf], acc[mr][nf], 0, 0, 0);
                        acc[mr][nf] = __builtin_amdgcn_mfma_f32_16x16x32_bf16(ah[mr], bl[nf], acc[mr][nf], 0, 0, 0);
                    }
                __builtin_amdgcn_s_setprio(0);
            }
        }

#pragma unroll
        for (int mr = 0; mr < 4; ++mr)
#pragma unroll
            for (int nf = 0; nf < 2; ++nf) acc[mr][nf] *= 0.03125f;   // 1/sqrt(1024)

        // ---- block row-max ----
#pragma unroll
        for (int mr = 0; mr < 4; ++mr)
#pragma unroll
            for (int g = 0; g < 4; ++g) {
                float m = fmaxf(acc[mr][0][g], acc[mr][1][g]);
#pragma unroll
                for (int msk = 1; msk <= 8; msk <<= 1)
                    m = fmaxf(m, __shfl_xor(m, msk, 64));
                if (l15 == 0) smaxf[(mr * 16 + lk * 4 + g) * 8 + w] = m;
            }
        __syncthreads();

        float m_new[4][4], corr[4][4], psum[4][4];
        bool resc = false;
#pragma unroll
        for (int mr = 0; mr < 4; ++mr)
#pragma unroll
            for (int g = 0; g < 4; ++g) {
                int r = mr * 16 + lk * 4 + g;
                float4 v0 = *(const float4*)&smaxf[r * 8];
                float4 v1 = *(const float4*)&smaxf[r * 8 + 4];
                float mn = fmaxf(fmaxf(fmaxf(v0.x, v0.y), fmaxf(v0.z, v0.w)),
                                 fmaxf(fmaxf(v1.x, v1.y), fmaxf(v1.z, v1.w)));
                if (mn - m_run[mr][g] > 8.0f) {    // defer-max (T13)
                    m_new[mr][g] = mn;
                    corr[mr][g]  = __expf(m_run[mr][g] - mn);
                    resc = true;
                } else {
                    m_new[mr][g] = m_run[mr][g];
                    corr[mr][g]  = 1.0f;
                }
                psum[mr][g] = 0.f;
            }

        // ---- p = exp(s-m): write P (bf16, swizzled), partial sums ----
#pragma unroll
        for (int mr = 0; mr < 4; ++mr)
#pragma unroll
            for (int nf = 0; nf < 2; ++nf)
#pragma unroll
                for (int g = 0; g < 4; ++g) {
                    int r = mr * 16 + lk * 4 + g;
                    float p = __expf(acc[mr][nf][g] - m_new[mr][g]);
                    psum[mr][g] += p;
                    int cL = w * 32 + nf * 16 + l15;
                    *(unsigned short*)&plds[r * 512 +
                        (((cL >> 3) ^ (r & 7)) << 4) + (cL & 7) * 2] = f2bf(p);
                }
#pragma unroll
        for (int mr = 0; mr < 4; ++mr)
#pragma unroll
            for (int g = 0; g < 4; ++g) {
                float sm = psum[mr][g];
#pragma unroll
                for (int msk = 1; msk <= 8; msk <<= 1) sm += __shfl_xor(sm, msk, 64);
                if (l15 == 0) ssumf[(mr * 16 + lk * 4 + g) * 8 + w] = sm;
            }
        __syncthreads();   // ssum + P visible

#pragma unroll
        for (int mr = 0; mr < 4; ++mr)
#pragma unroll
            for (int g = 0; g < 4; ++g) {
                int r = mr * 16 + lk * 4 + g;
                float4 v0 = *(const float4*)&ssumf[r * 8];
                float4 v1 = *(const float4*)&ssumf[r * 8 + 4];
                float lt = v0.x + v0.y + v0.z + v0.w + v1.x + v1.y + v1.z + v1.w;
                l_run[mr][g] = l_run[mr][g] * corr[mr][g] + lt;
                m_run[mr][g] = m_new[mr][g];
            }
        if (resc) {
#pragma unroll
            for (int mr = 0; mr < 4; ++mr)
#pragma unroll
                for (int nf = 0; nf < 8; ++nf)
#pragma unroll
                    for (int g = 0; g < 4; ++g) o[mr][nf][g] *= corr[mr][g];
        }

        // ---- O += P . X  (P from LDS, X^T direct from global) ----
#pragma unroll
        for (int ks2 = 0; ks2 < 8; ++ks2) {
            bf16x8 xb[8];
#pragma unroll
            for (int nf = 0; nf < 8; ++nf) {
                size_t off = (size_t)(w * 128 + nf * 16 + l15) * NR +
                             k0 + ks2 * 32 + lk * 8;
                xb[nf] = *(const bf16x8*)(XT + off);
            }
            bf16x8 pa[4];
#pragma unroll
            for (int mr = 0; mr < 4; ++mr) {
                int r = mr * 16 + l15;
                pa[mr] = *(const bf16x8*)&plds[r * 512 +
                                               (((ks2 * 4 + lk) ^ (r & 7)) << 4)];
            }
            __builtin_amdgcn_s_setprio(1);
#pragma unroll
            for (int mr = 0; mr < 4; ++mr)
#pragma unroll
                for (int nf = 0; nf < 8; ++nf)
                    o[mr][nf] = __builtin_amdgcn_mfma_f32_16x16x32_bf16(pa[mr], xb[nf], o[mr][nf], 0, 0, 0);
            __builtin_amdgcn_s_setprio(0);
        }
    }

    // ---- epilogue ----
    if (SPLIT) {
#pragma unroll
        for (int mr = 0; mr < 4; ++mr)
#pragma unroll
            for (int g = 0; g < 4; ++g) {
                int r = mr * 16 + lk * 4 + g;
                float inv = 1.0f / l_run[mr][g];
#pragma unroll
                for (int nf = 0; nf < 8; ++nf)
                    On[(size_t)sp * NR * DD + (size_t)(q0 + r) * DD +
                       w * 128 + nf * 16 + l15] = f2bf(o[mr][nf][g] * inv);
                if (w == 0 && l15 == 0) {
                    mlbuf[(size_t)sp * NR + q0 + r]          = m_run[mr][g];
                    mlbuf[4 * NR + (size_t)sp * NR + q0 + r] = l_run[mr][g];
                }
            }
    } else {
#pragma unroll
        for (int mr = 0; mr < 4; ++mr)
#pragma unroll
            for (int g = 0; g < 4; ++g) {
                int r = q0 + mr * 16 + lk * 4 + g;
                float inv = 1.0f / l_run[mr][g];
#pragma unroll
                for (int nf = 0; nf < 8; ++nf)
                    outp[(size_t)r * DD + w * 128 + nf * 16 + l15] = o[mr][nf][g] * inv;
            }
    }
}

// ---------------------------------------------------------------------------
// Combine the four KV-split partials: out = sum_i w_i * O_i_norm
// ---------------------------------------------------------------------------
__global__ __launch_bounds__(256) void combine4(const unsigned short* __restrict__ On,
                                                const float* __restrict__ mlbuf,
                                                float* __restrict__ outp) {
    const int r = blockIdx.x;
    float m = -3.0e38f;
#pragma unroll
    for (int i = 0; i < 4; ++i) m = fmaxf(m, mlbuf[(size_t)i * NR + r]);
    float wgt[4];
    float tot = 0.f;
#pragma unroll
    for (int i = 0; i < 4; ++i) {
        wgt[i] = mlbuf[4 * NR + (size_t)i * NR + r] *
                 __expf(mlbuf[(size_t)i * NR + r] - m);
        tot += wgt[i];
    }
    float inv = 1.0f / tot;
#pragma unroll
    for (int i = 0; i < 4; ++i) wgt[i] *= inv;

    const int d = threadIdx.x * 4;
    float4 v = make_float4(0.f, 0.f, 0.f, 0.f);
#pragma unroll
    for (int i = 0; i < 4; ++i) {
        u16x4 a = *(const u16x4*)(On + (size_t)i * NR * DD + (size_t)r * DD + d);
        v.x += wgt[i] * bf2f(a.x);
        v.y += wgt[i] * bf2f(a.y);
        v.z += wgt[i] * bf2f(a.z);
        v.w += wgt[i] * bf2f(a.w);
    }
    *(float4*)(outp + (size_t)r * DD + d) = v;
}

extern "C" void kernel_launch(void* const* d_in, const int* in_sizes, int n_in,
                              void* d_out, int out_size, void* d_ws, size_t ws_size,
                              hipStream_t stream) {
    const float* X  = (const float*)d_in[0];
    const float* Wq = (const float*)d_in[1];
    const float* Wk = (const float*)d_in[2];

    char* qpack = (char*)d_out;                        // [Qhi|Qlo] 4KB/row
    unsigned short* khi = (unsigned short*)d_ws;       // 16 MiB
    unsigned short* klo = khi + (size_t)NR * DD;       // 16 MiB
    unsigned short* xt  = klo + (size_t)NR * DD;       // 16 MiB
    unsigned short* On  = xt + (size_t)DD * NR;        // 64 MiB (4 splits)
    float* mlbuf        = (float*)(On + (size_t)4 * NR * DD);  // 256 KiB

    const size_t need_split = (size_t)NR * DD * 2 * 3 * 2   // khi,klo,xt
                            + (size_t)4 * NR * DD * 2       // On
                            + (size_t)8 * NR * 4;           // mlbuf

    dim3 pgrid(DD / 64, NR / 64);
    proj_gemm<0><<<pgrid, 256, 0, stream>>>(X, Wq, qpack, nullptr, nullptr);
    proj_gemm<1><<<pgrid, 256, 0, stream>>>(X, Wk, nullptr, khi, klo);
    prep_xt<<<dim3(NR / 64, DD / 64), 256, 0, stream>>>(X, xt);

    if (ws_size >= need_split) {
        flash4<true><<<NR / 64 * 4, 512, 0, stream>>>(qpack, khi, klo, xt,
                                                      nullptr, On, mlbuf);
        combine4<<<NR, 256, 0, stream>>>(On, mlbuf, (float*)d_out);
    } else {
        flash4<false><<<NR / 64, 512, 0, stream>>>(qpack, khi, klo, xt,
                                                   (float*)d_out, nullptr, nullptr);
    }
}

// Round 6
// 2853.151 us; speedup vs baseline: 1.4218x; 1.4218x over previous
//
#include <hip/hip_runtime.h>
#include <hip/hip_bf16.h>
#include <math.h>

#define NR 8192
#define DD 1024

typedef __attribute__((ext_vector_type(8))) short bf16x8;
typedef __attribute__((ext_vector_type(4))) float f32x4;

struct u16x4 { unsigned short x, y, z, w; };

__device__ __forceinline__ unsigned short f2bf(float v) {
    __hip_bfloat16 h = __float2bfloat16(v);
    return *(unsigned short*)&h;
}
__device__ __forceinline__ float bf2f(unsigned short u) {
    __hip_bfloat16 h = *(__hip_bfloat16*)&u;
    return __bfloat162float(h);
}

// async global->LDS: 16B/lane, LDS dest = wave-uniform base + lane*16
__device__ __forceinline__ void dma16(const void* g, void* l) {
    __builtin_amdgcn_global_load_lds(
        (const __attribute__((address_space(1))) unsigned int*)g,
        (__attribute__((address_space(3))) unsigned int*)l, 16, 0, 0);
}

#define WAIT_VM0 asm volatile("s_waitcnt vmcnt(0)" ::: "memory")
#define WAIT_LG0 asm volatile("s_waitcnt lgkmcnt(0)" ::: "memory")
#define BARRIER  asm volatile("s_barrier" ::: "memory")

// ---------------------------------------------------------------------------
// Projection GEMM (fp32, known-good).
// ---------------------------------------------------------------------------
template <int MODE>
__global__ __launch_bounds__(256) void proj_gemm(const float* __restrict__ X,
                                                 const float* __restrict__ W,
                                                 char* qpack,
                                                 unsigned short* khi,
                                                 unsigned short* klo) {
    __shared__ float As[16][64];
    __shared__ float Bs[16][64];

    const int tid = threadIdx.x;
    const int tx = tid & 15;
    const int ty = tid >> 4;
    const int m0 = blockIdx.y * 64;
    const int n0 = blockIdx.x * 64;

    const int lm  = tid >> 2;
    const int lk4 = (tid & 3) * 4;
    const int bk  = tid >> 4;
    const int bn4 = (tid & 15) * 4;

    float acc[4][4] = {};

    for (int kb = 0; kb < DD; kb += 16) {
        float4 av = *(const float4*)(X + (size_t)(m0 + lm) * DD + kb + lk4);
        As[lk4 + 0][lm] = av.x;
        As[lk4 + 1][lm] = av.y;
        As[lk4 + 2][lm] = av.z;
        As[lk4 + 3][lm] = av.w;
        *(float4*)&Bs[bk][bn4] =
            *(const float4*)(W + (size_t)(kb + bk) * DD + n0 + bn4);
        __syncthreads();
#pragma unroll
        for (int k = 0; k < 16; ++k) {
            float4 a = *(const float4*)&As[k][ty * 4];
            float4 b = *(const float4*)&Bs[k][tx * 4];
            float aa[4] = {a.x, a.y, a.z, a.w};
            float bb[4] = {b.x, b.y, b.z, b.w};
#pragma unroll
            for (int i = 0; i < 4; ++i)
#pragma unroll
                for (int j = 0; j < 4; ++j) acc[i][j] += aa[i] * bb[j];
        }
        __syncthreads();
    }
#pragma unroll
    for (int i = 0; i < 4; ++i) {
        int row = m0 + ty * 4 + i;
        int col = n0 + tx * 4;
        u16x4 hi, lo;
        float v0 = acc[i][0], v1 = acc[i][1], v2 = acc[i][2], v3 = acc[i][3];
        hi.x = f2bf(v0); lo.x = f2bf(v0 - bf2f(hi.x));
        hi.y = f2bf(v1); lo.y = f2bf(v1 - bf2f(hi.y));
        hi.z = f2bf(v2); lo.z = f2bf(v2 - bf2f(hi.z));
        hi.w = f2bf(v3); lo.w = f2bf(v3 - bf2f(hi.w));
        if (MODE == 0) {
            *(u16x4*)(qpack + (size_t)row * 4096 + col * 2)        = hi;
            *(u16x4*)(qpack + (size_t)row * 4096 + 2048 + col * 2) = lo;
        } else {
            *(u16x4*)(khi + (size_t)row * 1024 + col) = hi;
            *(u16x4*)(klo + (size_t)row * 1024 + col) = lo;
        }
    }
}

// ---------------------------------------------------------------------------
// X^T bf16: XT[1024][8192] = bf16(X)^T
// ---------------------------------------------------------------------------
__global__ __launch_bounds__(256) void prep_xt(const float* __restrict__ X,
                                               unsigned short* __restrict__ XT) {
    __shared__ float t[64][65];
    const int r0 = blockIdx.x * 64;
    const int c0 = blockIdx.y * 64;
    const int tid = threadIdx.x;
    const int tr = tid >> 6;
    const int tc = tid & 63;
#pragma unroll
    for (int rep = 0; rep < 16; ++rep) {
        int r = rep * 4 + tr;
        t[r][tc] = X[(size_t)(r0 + r) * DD + c0 + tc];
    }
    __syncthreads();
#pragma unroll
    for (int rep = 0; rep < 16; ++rep) {
        int c = rep * 4 + tr;
        XT[(size_t)(c0 + c) * NR + r0 + tc] = f2bf(t[tc][c]);
    }
}

// ---------------------------------------------------------------------------
// flash6: BM=64, KVBLK=128, 512 thr = 8 waves (1x8 over kv, 16 kv/wave).
// K staged via shared-LDS global_load_lds DMA, dbuf over 8 D-chunks of 128.
// Q reg-staged (T14) into single 32KB buffer. XT direct global in PV.
// LDS map (160KB):
//   K slot0 [0,64K): hi[128][256B] + lo at +32K ; slot1 [64K,128K)
//   Q [131072,163840): hi[64][256B] + lo at +16K
//   aliases after S phase (inside dead slot0): P [0,16K), smax [16K,18K),
//   ssum [18K,20K)
// All LDS 16B slots XOR-swizzled: phys p = j ^ (row&7); DMA pre-swizzles the
// global source column so fragment reads are bank-conflict-free.
// ---------------------------------------------------------------------------
template <bool SPLIT>
__global__ __launch_bounds__(512, 2) void flash6(
        const char* __restrict__ qpk,
        const unsigned short* __restrict__ Khi,
        const unsigned short* __restrict__ Klo,
        const unsigned short* __restrict__ XT,
        float* __restrict__ outp,
        unsigned short* __restrict__ On,
        float* __restrict__ mlbuf) {
    __shared__ __align__(128) char lds[163840];
    const int QBASE = 131072;

    const int tid = threadIdx.x;
    const int l   = tid & 63;
    const int w   = tid >> 6;
    const int l15 = l & 15;
    const int lk  = l >> 4;          // 0..3
    const int swz = l15 & 7;

    int qb, sp;
    if (SPLIT) { qb = blockIdx.x >> 1; sp = blockIdx.x & 1; }
    else       { qb = blockIdx.x;      sp = 0; }
    const int q0  = qb * 64;
    const int kv0 = SPLIT ? sp * (NR / 2) : 0;
    const int kv1 = SPLIT ? kv0 + (NR / 2) : NR;

    // --- K DMA per-lane constants: instr i covers rows w*16+i*4 .. +4 ---
    // lane -> row offset lk (=l>>4), phys slot l15; source col-slot j = l15 ^ (row&7)
    size_t kofs[4];
#pragma unroll
    for (int i = 0; i < 4; ++i) {
        int rr = i * 4 + lk;                   // row within wave band (w*16 ≡ 0 mod 8)
        int j  = l15 ^ (rr & 7);
        kofs[i] = (size_t)(w * 16 + rr) * 1024 + j * 8;   // shorts
    }

    // --- Q reg-stage per-thread constants (4 slots of 16B) ---
    size_t qsrc[4];
    int    qdst[4];
#pragma unroll
    for (int rep = 0; rep < 4; ++rep) {
        int s    = rep * 512 + tid;            // 0..2047
        int arr  = s >> 10;                    // 0 hi, 1 lo
        int qrow = (s >> 4) & 63;
        int qp   = s & 15;
        int qj   = qp ^ (qrow & 7);
        qsrc[rep] = (size_t)(q0 + qrow) * 4096 + arr * 2048 + qj * 16;  // + c*256
        qdst[rep] = QBASE + arr * 16384 + qrow * 256 + qp * 16;
    }

    f32x4 o[4][8];
    float m_run[4][4], l_run[4][4];
#pragma unroll
    for (int mr = 0; mr < 4; ++mr) {
#pragma unroll
        for (int nf = 0; nf < 8; ++nf) o[mr][nf] = f32x4{0.f, 0.f, 0.f, 0.f};
#pragma unroll
        for (int g = 0; g < 4; ++g) { m_run[mr][g] = -3.0e38f; l_run[mr][g] = 0.f; }
    }

    bf16x8 qreg[4];

    // ---- prologue: issue K[tile0, c=0] into slot0; load Q[0] regs ----
#pragma unroll
    for (int i = 0; i < 4; ++i) {
        dma16(Khi + (size_t)kv0 * 1024 + kofs[i], &lds[(w * 16 + i * 4) * 256]);
        dma16(Klo + (size_t)kv0 * 1024 + kofs[i], &lds[32768 + (w * 16 + i * 4) * 256]);
    }
#pragma unroll
    for (int rep = 0; rep < 4; ++rep)
        qreg[rep] = *(const bf16x8*)(qpk + qsrc[rep]);

    for (int k0 = kv0; k0 < kv1; k0 += 128) {
        f32x4 acc[4];
#pragma unroll
        for (int mr = 0; mr < 4; ++mr) acc[mr] = f32x4{0.f, 0.f, 0.f, 0.f};

        // ---- S phase: 8 D-chunks of 128 ----
#pragma unroll
        for (int c = 0; c < 8; ++c) {
            const int sl = c & 1;
            WAIT_VM0;            // K[c] landed (this wave's DMAs), Q[c] regs ready
            BARRIER;             // all waves' K[c] visible; Q[c-1] reads done
#pragma unroll
            for (int rep = 0; rep < 4; ++rep)
                *(bf16x8*)&lds[qdst[rep]] = qreg[rep];
            WAIT_LG0;
            BARRIER;             // Q[c] visible

            if (c < 7) {         // prefetch next chunk
                const int nsl = (c + 1) & 1;
#pragma unroll
                for (int i = 0; i < 4; ++i) {
                    size_t go = (size_t)k0 * 1024 + kofs[i] + (c + 1) * 128;
                    dma16(Khi + go, &lds[nsl * 65536 + (w * 16 + i * 4) * 256]);
                    dma16(Klo + go, &lds[nsl * 65536 + 32768 + (w * 16 + i * 4) * 256]);
                }
#pragma unroll
                for (int rep = 0; rep < 4; ++rep)
                    qreg[rep] = *(const bf16x8*)(qpk + qsrc[rep] + (c + 1) * 256);
            }

#pragma unroll
            for (int ks = 0; ks < 4; ++ks) {
                const int pslot = ((ks * 4 + lk) ^ swz) << 4;
                bf16x8 bh = *(const bf16x8*)&lds[sl * 65536 + (w * 16 + l15) * 256 + pslot];
                bf16x8 bl = *(const bf16x8*)&lds[sl * 65536 + 32768 + (w * 16 + l15) * 256 + pslot];
                bf16x8 ah[4], al[4];
#pragma unroll
                for (int mr = 0; mr < 4; ++mr) {
                    int off = (mr * 16 + l15) * 256 + pslot;
                    ah[mr] = *(const bf16x8*)&lds[QBASE + off];
                    al[mr] = *(const bf16x8*)&lds[QBASE + 16384 + off];
                }
                __builtin_amdgcn_s_setprio(1);
#pragma unroll
                for (int mr = 0; mr < 4; ++mr) {
                    acc[mr] = __builtin_amdgcn_mfma_f32_16x16x32_bf16(ah[mr], bh, acc[mr], 0, 0, 0);
                    acc[mr] = __builtin_amdgcn_mfma_f32_16x16x32_bf16(al[mr], bh, acc[mr], 0, 0, 0);
                    acc[mr] = __builtin_amdgcn_mfma_f32_16x16x32_bf16(ah[mr], bl, acc[mr], 0, 0, 0);
                }
                __builtin_amdgcn_s_setprio(0);
            }
        }
        // after c=7: slot0 reads ended at c=6 entry barrier -> P/smax/ssum
        // (all inside slot0) are safe to write per-wave now.

#pragma unroll
        for (int mr = 0; mr < 4; ++mr) acc[mr] *= 0.03125f;   // 1/sqrt(1024)

        float* smaxf = (float*)&lds[16384];
        float* ssumf = (float*)&lds[18432];

        // ---- wave-local row max over its 16 kv cols, then cross-wave ----
#pragma unroll
        for (int mr = 0; mr < 4; ++mr)
#pragma unroll
            for (int g = 0; g < 4; ++g) {
                float m = acc[mr][g];
#pragma unroll
                for (int msk = 1; msk <= 8; msk <<= 1)
                    m = fmaxf(m, __shfl_xor(m, msk, 64));
                if (l15 == 0) smaxf[(mr * 16 + lk * 4 + g) * 8 + w] = m;
            }
        WAIT_LG0; BARRIER;

        float m_new[4][4], corr[4][4];
        bool resc = false;
#pragma unroll
        for (int mr = 0; mr < 4; ++mr)
#pragma unroll
            for (int g = 0; g < 4; ++g) {
                int r = mr * 16 + lk * 4 + g;
                float4 v0 = *(const float4*)&smaxf[r * 8];
                float4 v1 = *(const float4*)&smaxf[r * 8 + 4];
                float mn = fmaxf(fmaxf(fmaxf(v0.x, v0.y), fmaxf(v0.z, v0.w)),
                                 fmaxf(fmaxf(v1.x, v1.y), fmaxf(v1.z, v1.w)));
                if (mn - m_run[mr][g] > 8.0f) {      // defer-max (T13)
                    m_new[mr][g] = mn;
                    corr[mr][g]  = __expf(m_run[mr][g] - mn);
                    resc = true;
                } else {
                    m_new[mr][g] = m_run[mr][g];
                    corr[mr][g]  = 1.0f;
                }
            }

        // ---- p = exp(s-m): write P (bf16, swizzled), partial sums ----
#pragma unroll
        for (int mr = 0; mr < 4; ++mr)
#pragma unroll
            for (int g = 0; g < 4; ++g) {
                int r = mr * 16 + lk * 4 + g;
                float p = __expf(acc[mr][g] - m_new[mr][g]);
                int cL = w * 16 + l15;
                *(unsigned short*)&lds[r * 256 +
                    (((cL >> 3) ^ (r & 7)) << 4) + (cL & 7) * 2] = f2bf(p);
                float sm = p;
#pragma unroll
                for (int msk = 1; msk <= 8; msk <<= 1) sm += __shfl_xor(sm, msk, 64);
                if (l15 == 0) ssumf[r * 8 + w] = sm;
            }
        WAIT_LG0; BARRIER;    // P + ssum visible

#pragma unroll
        for (int mr = 0; mr < 4; ++mr)
#pragma unroll
            for (int g = 0; g < 4; ++g) {
                int r = mr * 16 + lk * 4 + g;
                float4 v0 = *(const float4*)&ssumf[r * 8];
                float4 v1 = *(const float4*)&ssumf[r * 8 + 4];
                float lt = v0.x + v0.y + v0.z + v0.w + v1.x + v1.y + v1.z + v1.w;
                l_run[mr][g] = l_run[mr][g] * corr[mr][g] + lt;
                m_run[mr][g] = m_new[mr][g];
            }
        if (resc) {
#pragma unroll
            for (int mr = 0; mr < 4; ++mr)
#pragma unroll
                for (int nf = 0; nf < 8; ++nf)
#pragma unroll
                    for (int g = 0; g < 4; ++g) o[mr][nf][g] *= corr[mr][g];
        }

        // ---- O += P . X  (P from LDS, XT direct global) ----
#pragma unroll
        for (int ks2 = 0; ks2 < 4; ++ks2) {
            bf16x8 xb[8];
#pragma unroll
            for (int nf = 0; nf < 8; ++nf) {
                size_t off = (size_t)(w * 128 + nf * 16 + l15) * NR +
                             k0 + ks2 * 32 + lk * 8;
                xb[nf] = *(const bf16x8*)(XT + off);
            }
            bf16x8 pa[4];
#pragma unroll
            for (int mr = 0; mr < 4; ++mr) {
                int r = mr * 16 + l15;
                pa[mr] = *(const bf16x8*)&lds[r * 256 +
                                              (((ks2 * 4 + lk) ^ (r & 7)) << 4)];
            }
            __builtin_amdgcn_s_setprio(1);
#pragma unroll
            for (int mr = 0; mr < 4; ++mr)
#pragma unroll
                for (int nf = 0; nf < 8; ++nf)
                    o[mr][nf] = __builtin_amdgcn_mfma_f32_16x16x32_bf16(pa[mr], xb[nf], o[mr][nf], 0, 0, 0);
            __builtin_amdgcn_s_setprio(0);
        }

        WAIT_LG0; BARRIER;    // all P reads done -> slot0 free for next tile K

        if (k0 + 128 < kv1) {  // prefetch next tile chunk0
#pragma unroll
            for (int i = 0; i < 4; ++i) {
                size_t go = (size_t)(k0 + 128) * 1024 + kofs[i];
                dma16(Khi + go, &lds[(w * 16 + i * 4) * 256]);
                dma16(Klo + go, &lds[32768 + (w * 16 + i * 4) * 256]);
            }
#pragma unroll
            for (int rep = 0; rep < 4; ++rep)
                qreg[rep] = *(const bf16x8*)(qpk + qsrc[rep]);
        }
    }

    // ---- epilogue ----
    if (SPLIT) {
#pragma unroll
        for (int mr = 0; mr < 4; ++mr)
#pragma unroll
            for (int g = 0; g < 4; ++g) {
                int r = mr * 16 + lk * 4 + g;
                float inv = 1.0f / l_run[mr][g];
#pragma unroll
                for (int nf = 0; nf < 8; ++nf)
                    On[(size_t)sp * NR * DD + (size_t)(q0 + r) * DD +
                       w * 128 + nf * 16 + l15] = f2bf(o[mr][nf][g] * inv);
                if (w == 0 && l15 == 0) {
                    mlbuf[(size_t)sp * NR + q0 + r]          = m_run[mr][g];
                    mlbuf[2 * NR + (size_t)sp * NR + q0 + r] = l_run[mr][g];
                }
            }
    } else {
#pragma unroll
        for (int mr = 0; mr < 4; ++mr)
#pragma unroll
            for (int g = 0; g < 4; ++g) {
                int r = q0 + mr * 16 + lk * 4 + g;
                float inv = 1.0f / l_run[mr][g];
#pragma unroll
                for (int nf = 0; nf < 8; ++nf)
                    outp[(size_t)r * DD + w * 128 + nf * 16 + l15] = o[mr][nf][g] * inv;
            }
    }
}

// ---------------------------------------------------------------------------
// Combine the two KV-split partials
// ---------------------------------------------------------------------------
__global__ __launch_bounds__(256) void combine2(const unsigned short* __restrict__ On,
                                                const float* __restrict__ mlbuf,
                                                float* __restrict__ outp) {
    const int r = blockIdx.x;
    float m1 = mlbuf[r],          m2 = mlbuf[NR + r];
    float l1 = mlbuf[2 * NR + r], l2 = mlbuf[3 * NR + r];
    float m  = fmaxf(m1, m2);
    float w1 = l1 * __expf(m1 - m);
    float w2 = l2 * __expf(m2 - m);
    float inv = 1.0f / (w1 + w2);
    w1 *= inv; w2 *= inv;
    const int d = threadIdx.x * 4;
    u16x4 a = *(const u16x4*)(On + (size_t)r * DD + d);
    u16x4 b = *(const u16x4*)(On + (size_t)NR * DD + (size_t)r * DD + d);
    float4 v;
    v.x = w1 * bf2f(a.x) + w2 * bf2f(b.x);
    v.y = w1 * bf2f(a.y) + w2 * bf2f(b.y);
    v.z = w1 * bf2f(a.z) + w2 * bf2f(b.z);
    v.w = w1 * bf2f(a.w) + w2 * bf2f(b.w);
    *(float4*)(outp + (size_t)r * DD + d) = v;
}

extern "C" void kernel_launch(void* const* d_in, const int* in_sizes, int n_in,
                              void* d_out, int out_size, void* d_ws, size_t ws_size,
                              hipStream_t stream) {
    const float* X  = (const float*)d_in[0];
    const float* Wq = (const float*)d_in[1];
    const float* Wk = (const float*)d_in[2];

    char* qpack = (char*)d_out;                        // [Qhi|Qlo] 4KB/row
    unsigned short* khi = (unsigned short*)d_ws;       // 16 MiB
    unsigned short* klo = khi + (size_t)NR * DD;       // 16 MiB
    unsigned short* xt  = klo + (size_t)NR * DD;       // 16 MiB
    unsigned short* On  = xt + (size_t)DD * NR;        // 32 MiB (2 splits)
    float* mlbuf        = (float*)(On + (size_t)2 * NR * DD);  // 128 KiB

    const size_t need_split = (size_t)NR * DD * 2 * 3 * 2
                            + (size_t)2 * NR * DD * 2
                            + (size_t)4 * NR * 4;

    dim3 pgrid(DD / 64, NR / 64);
    proj_gemm<0><<<pgrid, 256, 0, stream>>>(X, Wq, qpack, nullptr, nullptr);
    proj_gemm<1><<<pgrid, 256, 0, stream>>>(X, Wk, nullptr, khi, klo);
    prep_xt<<<dim3(NR / 64, DD / 64), 256, 0, stream>>>(X, xt);

    if (ws_size >= need_split) {
        flash6<true><<<NR / 64 * 2, 512, 0, stream>>>(qpack, khi, klo, xt,
                                                      nullptr, On, mlbuf);
        combine2<<<NR, 256, 0, stream>>>(On, mlbuf, (float*)d_out);
    } else {
        flash6<false><<<NR / 64, 512, 0, stream>>>(qpack, khi, klo, xt,
                                                   (float*)d_out, nullptr, nullptr);
    }
}

// Round 7
// 1593.332 us; speedup vs baseline: 2.5459x; 1.7907x over previous
//
#include <hip/hip_runtime.h>
#include <hip/hip_bf16.h>
#include <math.h>

#define NR 8192
#define DD 1024
#define BAND 4096

typedef __attribute__((ext_vector_type(8))) short bf16x8;
typedef __attribute__((ext_vector_type(4))) float f32x4;
typedef unsigned short ushort_t;

struct u16x4 { unsigned short x, y, z, w; };

__device__ __forceinline__ unsigned short f2bf(float v) {
    __hip_bfloat16 h = __float2bfloat16(v);
    return *(unsigned short*)&h;
}
__device__ __forceinline__ float bf2f(unsigned short u) {
    __hip_bfloat16 h = *(__hip_bfloat16*)&u;
    return __bfloat162float(h);
}

#define WAIT_VM0 asm volatile("s_waitcnt vmcnt(0)" ::: "memory")
#define WAIT_LG0 asm volatile("s_waitcnt lgkmcnt(0)" ::: "memory")
#define BARRIER  __builtin_amdgcn_s_barrier()

// ---------------------------------------------------------------------------
// Projection GEMM (fp32, proven).
// MODE 0: per-row records [hi 2048B | lo 2048B] into qpack (d_out).
// MODE 1: khi/klo bf16 arrays (ws).
// ---------------------------------------------------------------------------
template <int MODE>
__global__ __launch_bounds__(256) void proj_gemm(const float* __restrict__ X,
                                                 const float* __restrict__ W,
                                                 char* qpack,
                                                 unsigned short* khi,
                                                 unsigned short* klo) {
    __shared__ float As[16][64];
    __shared__ float Bs[16][64];

    const int tid = threadIdx.x;
    const int tx = tid & 15;
    const int ty = tid >> 4;
    const int m0 = blockIdx.y * 64;
    const int n0 = blockIdx.x * 64;

    const int lm  = tid >> 2;
    const int lk4 = (tid & 3) * 4;
    const int bk  = tid >> 4;
    const int bn4 = (tid & 15) * 4;

    float acc[4][4] = {};

    for (int kb = 0; kb < DD; kb += 16) {
        float4 av = *(const float4*)(X + (size_t)(m0 + lm) * DD + kb + lk4);
        As[lk4 + 0][lm] = av.x;
        As[lk4 + 1][lm] = av.y;
        As[lk4 + 2][lm] = av.z;
        As[lk4 + 3][lm] = av.w;
        *(float4*)&Bs[bk][bn4] =
            *(const float4*)(W + (size_t)(kb + bk) * DD + n0 + bn4);
        __syncthreads();
#pragma unroll
        for (int k = 0; k < 16; ++k) {
            float4 a = *(const float4*)&As[k][ty * 4];
            float4 b = *(const float4*)&Bs[k][tx * 4];
            float aa[4] = {a.x, a.y, a.z, a.w};
            float bb[4] = {b.x, b.y, b.z, b.w};
#pragma unroll
            for (int i = 0; i < 4; ++i)
#pragma unroll
                for (int j = 0; j < 4; ++j) acc[i][j] += aa[i] * bb[j];
        }
        __syncthreads();
    }
#pragma unroll
    for (int i = 0; i < 4; ++i) {
        int row = m0 + ty * 4 + i;
        int col = n0 + tx * 4;
        u16x4 hi, lo;
        float v0 = acc[i][0], v1 = acc[i][1], v2 = acc[i][2], v3 = acc[i][3];
        hi.x = f2bf(v0); lo.x = f2bf(v0 - bf2f(hi.x));
        hi.y = f2bf(v1); lo.y = f2bf(v1 - bf2f(hi.y));
        hi.z = f2bf(v2); lo.z = f2bf(v2 - bf2f(hi.z));
        hi.w = f2bf(v3); lo.w = f2bf(v3 - bf2f(hi.w));
        if (MODE == 0) {
            *(u16x4*)(qpack + (size_t)row * 4096 + col * 2)        = hi;
            *(u16x4*)(qpack + (size_t)row * 4096 + 2048 + col * 2) = lo;
        } else {
            *(u16x4*)(khi + (size_t)row * 1024 + col) = hi;
            *(u16x4*)(klo + (size_t)row * 1024 + col) = lo;
        }
    }
}

// ---------------------------------------------------------------------------
// X^T bf16: XT[1024][8192] (PV B-operand layout)
// ---------------------------------------------------------------------------
__global__ __launch_bounds__(256) void prep_xt(const float* __restrict__ X,
                                               unsigned short* __restrict__ XT) {
    __shared__ float t[64][65];
    const int r0 = blockIdx.x * 64;
    const int c0 = blockIdx.y * 64;
    const int tid = threadIdx.x;
    const int tr = tid >> 6;
    const int tc = tid & 63;
#pragma unroll
    for (int rep = 0; rep < 16; ++rep) {
        int r = rep * 4 + tr;
        t[r][tc] = X[(size_t)(r0 + r) * DD + c0 + tc];
    }
    __syncthreads();
#pragma unroll
    for (int rep = 0; rep < 16; ++rep) {
        int c = rep * 4 + tr;
        XT[(size_t)(c0 + c) * NR + r0 + tc] = f2bf(t[tc][c]);
    }
}

// ---------------------------------------------------------------------------
// sgemm: T[128q x 128kv tile] = Q.K^T * scale - tilemax, bf16 out.
// 256 thr = 4 waves (2x2), wave 64x64, acc[4][4] (64 AGPR).
// A (Q hi/lo) LDS-staged per K64 (reg-staged, 8-slot XOR swizzle);
// B (K hi/lo) direct global. 3-product split-bf16.
// ---------------------------------------------------------------------------
__global__ __launch_bounds__(256) void sgemm(const char* __restrict__ qpk,
                                             const unsigned short* __restrict__ Khi,
                                             const unsigned short* __restrict__ Klo,
                                             unsigned short* __restrict__ Tb,
                                             float* __restrict__ mtile,
                                             int band) {
    __shared__ __align__(128) char alds[32768];   // Ah[128][128B] | Al at +16K
    __shared__ float rmax[128][2];

    const int tid = threadIdx.x;
    const int l   = tid & 63;
    const int w   = tid >> 6;
    const int wm  = w >> 1;
    const int wn  = w & 1;
    const int l15 = l & 15;
    const int lk  = l >> 4;
    const int swz = l15 & 7;

    const int kv0   = blockIdx.x * 128;
    const int trow0 = blockIdx.y * 128;                 // band-local
    const size_t qrow0 = (size_t)band * BAND + trow0;   // global

    // staging map: 2048 slots of 16B per K64; 8 per thread
    int srow[8], sj[8], sarr[8], sdst[8];
#pragma unroll
    for (int rep = 0; rep < 8; ++rep) {
        int s = rep * 256 + tid;
        sarr[rep] = s >> 10;
        srow[rep] = (s >> 3) & 127;
        sj[rep]   = s & 7;
        sdst[rep] = sarr[rep] * 16384 + srow[rep] * 128 +
                    ((sj[rep] ^ (srow[rep] & 7)) << 4);
    }

    f32x4 acc[4][4];
#pragma unroll
    for (int mr = 0; mr < 4; ++mr)
#pragma unroll
        for (int nf = 0; nf < 4; ++nf) acc[mr][nf] = f32x4{0.f, 0.f, 0.f, 0.f};

    bf16x8 qv[8];
#pragma unroll
    for (int rep = 0; rep < 8; ++rep)
        qv[rep] = *(const bf16x8*)(qpk + (qrow0 + srow[rep]) * 4096 +
                                   sarr[rep] * 2048 + sj[rep] * 16);

    for (int t = 0; t < 16; ++t) {
        WAIT_VM0;     // qv ready
        BARRIER;      // all waves done reading alds (prev t)
#pragma unroll
        for (int rep = 0; rep < 8; ++rep)
            *(bf16x8*)&alds[sdst[rep]] = qv[rep];
        if (t < 15) {
#pragma unroll
            for (int rep = 0; rep < 8; ++rep)
                qv[rep] = *(const bf16x8*)(qpk + (qrow0 + srow[rep]) * 4096 +
                                           sarr[rep] * 2048 + (t + 1) * 128 +
                                           sj[rep] * 16);
        }
        WAIT_LG0;
        BARRIER;      // tile t visible

#pragma unroll
        for (int ks = 0; ks < 2; ++ks) {
            const int kk = t * 64 + ks * 32 + lk * 8;
            bf16x8 bh[4], bl[4];
#pragma unroll
            for (int nf = 0; nf < 4; ++nf) {
                size_t off = (size_t)(kv0 + wn * 64 + nf * 16 + l15) * 1024 + kk;
                bh[nf] = *(const bf16x8*)(Khi + off);
                bl[nf] = *(const bf16x8*)(Klo + off);
            }
            bf16x8 ah[4], al[4];
#pragma unroll
            for (int mr = 0; mr < 4; ++mr) {
                int aoff = (wm * 64 + mr * 16 + l15) * 128 +
                           (((ks * 4 + lk) ^ swz) << 4);
                ah[mr] = *(const bf16x8*)&alds[aoff];
                al[mr] = *(const bf16x8*)&alds[16384 + aoff];
            }
            __builtin_amdgcn_s_setprio(1);
#pragma unroll
            for (int mr = 0; mr < 4; ++mr)
#pragma unroll
                for (int nf = 0; nf < 4; ++nf) {
                    acc[mr][nf] = __builtin_amdgcn_mfma_f32_16x16x32_bf16(ah[mr], bh[nf], acc[mr][nf], 0, 0, 0);
                    acc[mr][nf] = __builtin_amdgcn_mfma_f32_16x16x32_bf16(al[mr], bh[nf], acc[mr][nf], 0, 0, 0);
                    acc[mr][nf] = __builtin_amdgcn_mfma_f32_16x16x32_bf16(ah[mr], bl[nf], acc[mr][nf], 0, 0, 0);
                }
            __builtin_amdgcn_s_setprio(0);
        }
    }

    // ---- epilogue: scale, tile row-max, write T bf16 + mtile ----
#pragma unroll
    for (int mr = 0; mr < 4; ++mr)
#pragma unroll
        for (int nf = 0; nf < 4; ++nf) acc[mr][nf] *= 0.03125f;

#pragma unroll
    for (int mr = 0; mr < 4; ++mr)
#pragma unroll
        for (int g = 0; g < 4; ++g) {
            float m = fmaxf(fmaxf(acc[mr][0][g], acc[mr][1][g]),
                            fmaxf(acc[mr][2][g], acc[mr][3][g]));
#pragma unroll
            for (int msk = 1; msk <= 8; msk <<= 1)
                m = fmaxf(m, __shfl_xor(m, msk, 64));
            if (l15 == 0) rmax[wm * 64 + mr * 16 + lk * 4 + g][wn] = m;
        }
    __syncthreads();

#pragma unroll
    for (int mr = 0; mr < 4; ++mr)
#pragma unroll
        for (int g = 0; g < 4; ++g) {
            int r = wm * 64 + mr * 16 + lk * 4 + g;
            float mt = fmaxf(rmax[r][0], rmax[r][1]);
            if (wn == 0 && l15 == 0)
                mtile[(size_t)(trow0 + r) * 64 + blockIdx.x] = mt;
#pragma unroll
            for (int nf = 0; nf < 4; ++nf)
                Tb[(size_t)(trow0 + r) * 8192 + kv0 + wn * 64 + nf * 16 + l15] =
                    f2bf(acc[mr][nf][g] - mt);
        }
}

// ---------------------------------------------------------------------------
// softmax: one block per row; logits = T + mtile; P bf16 written in place.
// ---------------------------------------------------------------------------
__global__ __launch_bounds__(256) void softmax_row(unsigned short* __restrict__ Tb,
                                                   const float* __restrict__ mtile,
                                                   float* __restrict__ rinv) {
    __shared__ float red[8];
    const int r   = blockIdx.x;
    const int tid = threadIdx.x;
    const int l   = tid & 63;
    const int w   = tid >> 6;

    const float* mrow = mtile + (size_t)r * 64;
    unsigned short* trow = Tb + (size_t)r * 8192;

    bf16x8 tv[4];
    float  mt[4];
#pragma unroll
    for (int j = 0; j < 4; ++j) {
        int q = j * 256 + tid;           // 16B chunk id, coalesced
        tv[j] = *(const bf16x8*)(trow + q * 8);
        mt[j] = mrow[q >> 4];
    }

    float lm = -3.0e38f;
#pragma unroll
    for (int j = 0; j < 4; ++j)
#pragma unroll
        for (int e = 0; e < 8; ++e)
            lm = fmaxf(lm, bf2f((unsigned short)tv[j][e]) + mt[j]);
#pragma unroll
    for (int msk = 1; msk <= 32; msk <<= 1)
        lm = fmaxf(lm, __shfl_xor(lm, msk, 64));
    if (l == 0) red[w] = lm;
    __syncthreads();
    const float m = fmaxf(fmaxf(red[0], red[1]), fmaxf(red[2], red[3]));

    float ls = 0.f;
#pragma unroll
    for (int j = 0; j < 4; ++j) {
        bf16x8 pv;
#pragma unroll
        for (int e = 0; e < 8; ++e) {
            float p = __expf(bf2f((unsigned short)tv[j][e]) + mt[j] - m);
            ls += p;
            pv[e] = (short)f2bf(p);
        }
        int q = j * 256 + tid;
        *(bf16x8*)(trow + q * 8) = pv;
    }
#pragma unroll
    for (int msk = 1; msk <= 32; msk <<= 1)
        ls += __shfl_xor(ls, msk, 64);
    if (l == 0) red[4 + w] = ls;
    __syncthreads();
    if (tid == 0)
        rinv[r] = 1.0f / (red[4] + red[5] + red[6] + red[7]);
}

// ---------------------------------------------------------------------------
// pv: O_partial[128q x 128d tile] += P . X over one kv quarter (split-K 4).
// 256 thr = 4 waves (2x2), wave 64x64, acc[4][4].
// A (P) LDS-staged per K64; B (XT) direct global. bf16 partials out.
// ---------------------------------------------------------------------------
__global__ __launch_bounds__(256) void pv(const unsigned short* __restrict__ Pb,
                                          const unsigned short* __restrict__ XT,
                                          unsigned short* __restrict__ Opart) {
    __shared__ __align__(128) char plds[16384];   // P[128][128B]

    const int tid = threadIdx.x;
    const int l   = tid & 63;
    const int w   = tid >> 6;
    const int wm  = w >> 1;
    const int wn  = w & 1;
    const int l15 = l & 15;
    const int lk  = l >> 4;
    const int swz = l15 & 7;

    const int d0    = blockIdx.x * 128;
    const int trow0 = blockIdx.y * 128;
    const int sp    = blockIdx.z;
    const int kvb   = sp * 2048;

    int srow[4], sj[4], sdst[4];
#pragma unroll
    for (int rep = 0; rep < 4; ++rep) {
        int s = rep * 256 + tid;
        srow[rep] = s >> 3;
        sj[rep]   = s & 7;
        sdst[rep] = srow[rep] * 128 + ((sj[rep] ^ (srow[rep] & 7)) << 4);
    }

    f32x4 acc[4][4];
#pragma unroll
    for (int mr = 0; mr < 4; ++mr)
#pragma unroll
        for (int nf = 0; nf < 4; ++nf) acc[mr][nf] = f32x4{0.f, 0.f, 0.f, 0.f};

    bf16x8 pvreg[4];
#pragma unroll
    for (int rep = 0; rep < 4; ++rep)
        pvreg[rep] = *(const bf16x8*)(Pb + (size_t)(trow0 + srow[rep]) * 8192 +
                                      kvb + sj[rep] * 8);

    for (int t = 0; t < 32; ++t) {
        const int k = kvb + t * 64;
        WAIT_VM0;
        BARRIER;
#pragma unroll
        for (int rep = 0; rep < 4; ++rep)
            *(bf16x8*)&plds[sdst[rep]] = pvreg[rep];
        if (t < 31) {
#pragma unroll
            for (int rep = 0; rep < 4; ++rep)
                pvreg[rep] = *(const bf16x8*)(Pb + (size_t)(trow0 + srow[rep]) * 8192 +
                                              k + 64 + sj[rep] * 8);
        }
        WAIT_LG0;
        BARRIER;

#pragma unroll
        for (int ks = 0; ks < 2; ++ks) {
            const int kk = k + ks * 32 + lk * 8;
            bf16x8 xb[4];
#pragma unroll
            for (int nf = 0; nf < 4; ++nf)
                xb[nf] = *(const bf16x8*)(XT + (size_t)(d0 + wn * 64 + nf * 16 + l15) * NR + kk);
            bf16x8 pa[4];
#pragma unroll
            for (int mr = 0; mr < 4; ++mr)
                pa[mr] = *(const bf16x8*)&plds[(wm * 64 + mr * 16 + l15) * 128 +
                                               (((ks * 4 + lk) ^ swz) << 4)];
            __builtin_amdgcn_s_setprio(1);
#pragma unroll
            for (int mr = 0; mr < 4; ++mr)
#pragma unroll
                for (int nf = 0; nf < 4; ++nf)
                    acc[mr][nf] = __builtin_amdgcn_mfma_f32_16x16x32_bf16(pa[mr], xb[nf], acc[mr][nf], 0, 0, 0);
            __builtin_amdgcn_s_setprio(0);
        }
    }

#pragma unroll
    for (int mr = 0; mr < 4; ++mr)
#pragma unroll
        for (int g = 0; g < 4; ++g) {
            int r = trow0 + wm * 64 + mr * 16 + lk * 4 + g;
#pragma unroll
            for (int nf = 0; nf < 4; ++nf)
                Opart[((size_t)sp * BAND + r) * 1024 + d0 + wn * 64 + nf * 16 + l15] =
                    f2bf(acc[mr][nf][g]);
        }
}

// ---------------------------------------------------------------------------
// combine: out = (sum of 4 kv-split partials) * rinv
// ---------------------------------------------------------------------------
__global__ __launch_bounds__(256) void combine(const unsigned short* __restrict__ Opart,
                                               const float* __restrict__ rinv,
                                               float* __restrict__ outp,
                                               int band) {
    const int r = blockIdx.x;
    const int d = threadIdx.x * 4;
    const float ri = rinv[r];
    float4 v = make_float4(0.f, 0.f, 0.f, 0.f);
#pragma unroll
    for (int s = 0; s < 4; ++s) {
        u16x4 a = *(const u16x4*)(Opart + ((size_t)s * BAND + r) * 1024 + d);
        v.x += bf2f(a.x);
        v.y += bf2f(a.y);
        v.z += bf2f(a.z);
        v.w += bf2f(a.w);
    }
    v.x *= ri; v.y *= ri; v.z *= ri; v.w *= ri;
    *(float4*)(outp + ((size_t)band * BAND + r) * 1024 + d) = v;
}

extern "C" void kernel_launch(void* const* d_in, const int* in_sizes, int n_in,
                              void* d_out, int out_size, void* d_ws, size_t ws_size,
                              hipStream_t stream) {
    const float* X  = (const float*)d_in[0];
    const float* Wq = (const float*)d_in[1];
    const float* Wk = (const float*)d_in[2];

    char* qpack = (char*)d_out;                     // [Qhi|Qlo] 4KB/row (rows die per band)

    unsigned short* khi = (unsigned short*)d_ws;                 // 16 MiB
    unsigned short* klo = khi + (size_t)NR * DD;                 // 16 MiB
    unsigned short* xt  = klo + (size_t)NR * DD;                 // 16 MiB
    unsigned short* Tb  = xt + (size_t)DD * NR;                  // 64 MiB (band T/P, in place)
    float* mtile        = (float*)(Tb + (size_t)BAND * NR);      // 1 MiB
    float* rinv         = mtile + (size_t)BAND * 64;             // 16 KiB
    unsigned short* Opart = (unsigned short*)(rinv + BAND);      // 32 MiB (4 splits, bf16)

    dim3 pgrid(DD / 64, NR / 64);
    proj_gemm<0><<<pgrid, 256, 0, stream>>>(X, Wq, qpack, nullptr, nullptr);
    proj_gemm<1><<<pgrid, 256, 0, stream>>>(X, Wk, nullptr, khi, klo);
    prep_xt<<<dim3(NR / 64, DD / 64), 256, 0, stream>>>(X, xt);

    for (int band = 0; band < 2; ++band) {
        sgemm<<<dim3(NR / 128, BAND / 128), 256, 0, stream>>>(qpack, khi, klo,
                                                              Tb, mtile, band);
        softmax_row<<<BAND, 256, 0, stream>>>(Tb, mtile, rinv);
        pv<<<dim3(DD / 128, BAND / 128, 4), 256, 0, stream>>>(Tb, xt, Opart);
        combine<<<BAND, 256, 0, stream>>>(Opart, rinv, (float*)d_out, band);
    }
}

// Round 8
// 1012.067 us; speedup vs baseline: 4.0081x; 1.5743x over previous
//
#include <hip/hip_runtime.h>
#include <hip/hip_bf16.h>
#include <math.h>

#define NR 8192
#define DD 1024
#define BAND 4096

typedef __attribute__((ext_vector_type(8))) short bf16x8;
typedef __attribute__((ext_vector_type(4))) float f32x4;

struct u16x4 { unsigned short x, y, z, w; };

__device__ __forceinline__ unsigned short f2bf(float v) {
    __hip_bfloat16 h = __float2bfloat16(v);
    return *(unsigned short*)&h;
}
__device__ __forceinline__ float bf2f(unsigned short u) {
    __hip_bfloat16 h = *(__hip_bfloat16*)&u;
    return __bfloat162float(h);
}

// async global->LDS: 16B/lane; LDS dest = wave-uniform base + lane*16
__device__ __forceinline__ void dma16(const void* g, void* l) {
    __builtin_amdgcn_global_load_lds(
        (const __attribute__((address_space(1))) unsigned int*)g,
        (__attribute__((address_space(3))) unsigned int*)l, 16, 0, 0);
}

// ---------------------------------------------------------------------------
// Projection GEMM (fp32, proven).
// MODE 0: per-row records [hi 2048B | lo 2048B] into qpack (d_out).
// MODE 1: khi/klo bf16 arrays (ws).
// ---------------------------------------------------------------------------
template <int MODE>
__global__ __launch_bounds__(256) void proj_gemm(const float* __restrict__ X,
                                                 const float* __restrict__ W,
                                                 char* qpack,
                                                 unsigned short* khi,
                                                 unsigned short* klo) {
    __shared__ float As[16][64];
    __shared__ float Bs[16][64];

    const int tid = threadIdx.x;
    const int tx = tid & 15;
    const int ty = tid >> 4;
    const int m0 = blockIdx.y * 64;
    const int n0 = blockIdx.x * 64;

    const int lm  = tid >> 2;
    const int lk4 = (tid & 3) * 4;
    const int bk  = tid >> 4;
    const int bn4 = (tid & 15) * 4;

    float acc[4][4] = {};

    for (int kb = 0; kb < DD; kb += 16) {
        float4 av = *(const float4*)(X + (size_t)(m0 + lm) * DD + kb + lk4);
        As[lk4 + 0][lm] = av.x;
        As[lk4 + 1][lm] = av.y;
        As[lk4 + 2][lm] = av.z;
        As[lk4 + 3][lm] = av.w;
        *(float4*)&Bs[bk][bn4] =
            *(const float4*)(W + (size_t)(kb + bk) * DD + n0 + bn4);
        __syncthreads();
#pragma unroll
        for (int k = 0; k < 16; ++k) {
            float4 a = *(const float4*)&As[k][ty * 4];
            float4 b = *(const float4*)&Bs[k][tx * 4];
            float aa[4] = {a.x, a.y, a.z, a.w};
            float bb[4] = {b.x, b.y, b.z, b.w};
#pragma unroll
            for (int i = 0; i < 4; ++i)
#pragma unroll
                for (int j = 0; j < 4; ++j) acc[i][j] += aa[i] * bb[j];
        }
        __syncthreads();
    }
#pragma unroll
    for (int i = 0; i < 4; ++i) {
        int row = m0 + ty * 4 + i;
        int col = n0 + tx * 4;
        u16x4 hi, lo;
        float v0 = acc[i][0], v1 = acc[i][1], v2 = acc[i][2], v3 = acc[i][3];
        hi.x = f2bf(v0); lo.x = f2bf(v0 - bf2f(hi.x));
        hi.y = f2bf(v1); lo.y = f2bf(v1 - bf2f(hi.y));
        hi.z = f2bf(v2); lo.z = f2bf(v2 - bf2f(hi.z));
        hi.w = f2bf(v3); lo.w = f2bf(v3 - bf2f(hi.w));
        if (MODE == 0) {
            *(u16x4*)(qpack + (size_t)row * 4096 + col * 2)        = hi;
            *(u16x4*)(qpack + (size_t)row * 4096 + 2048 + col * 2) = lo;
        } else {
            *(u16x4*)(khi + (size_t)row * 1024 + col) = hi;
            *(u16x4*)(klo + (size_t)row * 1024 + col) = lo;
        }
    }
}

// ---------------------------------------------------------------------------
// X^T bf16: XT[1024][8192] (PV B-operand layout)
// ---------------------------------------------------------------------------
__global__ __launch_bounds__(256) void prep_xt(const float* __restrict__ X,
                                               unsigned short* __restrict__ XT) {
    __shared__ float t[64][65];
    const int r0 = blockIdx.x * 64;
    const int c0 = blockIdx.y * 64;
    const int tid = threadIdx.x;
    const int tr = tid >> 6;
    const int tc = tid & 63;
#pragma unroll
    for (int rep = 0; rep < 16; ++rep) {
        int r = rep * 4 + tr;
        t[r][tc] = X[(size_t)(r0 + r) * DD + c0 + tc];
    }
    __syncthreads();
#pragma unroll
    for (int rep = 0; rep < 16; ++rep) {
        int c = rep * 4 + tr;
        XT[(size_t)(c0 + c) * NR + r0 + tc] = f2bf(t[tc][c]);
    }
}

// ---------------------------------------------------------------------------
// sgemm2: T[256q x 256kv] = Q.K^T * scale - tilemax, bf16 out.
// 512 thr = 8 waves (2q x 4kv), wave 128x64 out, acc[8][4] (128 regs).
// BK=32; A and B staged via global_load_lds, double-buffered (2x64KB).
// LDS rows 128B = [hi 4 slots | lo 4 slots], XOR-swizzled (phys = j^(r&7))
// via pre-swizzled global source. One __syncthreads per K-step (its
// vmcnt(0) is the depth-1 counted wait: stage(t+1) issued BEFORE compute(t)).
// ---------------------------------------------------------------------------
__global__ __launch_bounds__(512, 2) void sgemm2(const char* __restrict__ qpk,
                                                 const unsigned short* __restrict__ Khi,
                                                 const unsigned short* __restrict__ Klo,
                                                 unsigned short* __restrict__ Tb,
                                                 float* __restrict__ mtile,
                                                 int band) {
    __shared__ __align__(128) char lds[131072];   // 2 x 64KB: [A 32K | B 32K]
    __shared__ float rmax[256][4];

    const int tid = threadIdx.x;
    const int l   = tid & 63;
    const int w   = tid >> 6;
    const int l15 = l & 15;
    const int lk  = l >> 4;          // 0..3  (k-group)
    const int swz = l15 & 7;
    const int wm  = w >> 2;          // 0..1  q strip (128)
    const int wn  = w & 3;           // 0..3  kv strip (64)

    const int kv0   = blockIdx.x * 256;
    const int trow0 = blockIdx.y * 256;                 // band-local
    const size_t qrow0 = (size_t)band * BAND + trow0;   // global q row

    // ---- DMA maps: 8 instr/thread/K-step; src advances 64B per t ----
    const char* src[8];
    int ldst[8];
#pragma unroll
    for (int d = 0; d < 4; ++d) {          // A = Q (hi|lo packed rows)
        int s = d * 512 + tid;
        int r = s >> 3, phys = s & 7;
        int j = phys ^ (r & 7);
        src[d]  = qpk + (qrow0 + r) * 4096 + (j >> 2) * 2048 + (j & 3) * 16;
        ldst[d] = d * 8192 + tid * 16;
    }
#pragma unroll
    for (int d = 4; d < 8; ++d) {          // B = K (hi|lo from two arrays)
        int s = (d - 4) * 512 + tid;
        int r = s >> 3, phys = s & 7;
        int j = phys ^ (r & 7);
        const unsigned short* base = (j >> 2) ? Klo : Khi;
        src[d]  = (const char*)(base + (size_t)(kv0 + r) * 1024 + (j & 3) * 8);
        ldst[d] = 32768 + (d - 4) * 8192 + tid * 16;
    }

    f32x4 acc[8][4];
#pragma unroll
    for (int mr = 0; mr < 8; ++mr)
#pragma unroll
        for (int nf = 0; nf < 4; ++nf) acc[mr][nf] = f32x4{0.f, 0.f, 0.f, 0.f};

    // ---- prologue: stage t=0 into buf0 ----
#pragma unroll
    for (int d = 0; d < 8; ++d) dma16(src[d], &lds[ldst[d]]);
    __syncthreads();

    for (int t = 0; t < 32; ++t) {
        const int cur = t & 1;
        if (t < 32 - 1) {
            const int nb = cur ^ 1;
#pragma unroll
            for (int d = 0; d < 8; ++d)
                dma16(src[d] + (t + 1) * 64, &lds[nb * 65536 + ldst[d]]);
        }
        const char* AB = &lds[cur * 65536];

        bf16x8 bh[4], bl[4];
#pragma unroll
        for (int nf = 0; nf < 4; ++nf) {
            int row = wn * 64 + nf * 16 + l15;
            bh[nf] = *(const bf16x8*)&AB[32768 + row * 128 + ((lk ^ swz) << 4)];
            bl[nf] = *(const bf16x8*)&AB[32768 + row * 128 + (((lk ^ 4) ^ swz) << 4)];
        }
#pragma unroll
        for (int half = 0; half < 2; ++half) {
            bf16x8 ah[4], al[4];
#pragma unroll
            for (int i = 0; i < 4; ++i) {
                int row = wm * 128 + (half * 4 + i) * 16 + l15;
                ah[i] = *(const bf16x8*)&AB[row * 128 + ((lk ^ swz) << 4)];
                al[i] = *(const bf16x8*)&AB[row * 128 + (((lk ^ 4) ^ swz) << 4)];
            }
            __builtin_amdgcn_s_setprio(1);
#pragma unroll
            for (int i = 0; i < 4; ++i) {
                int mr = half * 4 + i;
#pragma unroll
                for (int nf = 0; nf < 4; ++nf) {
                    acc[mr][nf] = __builtin_amdgcn_mfma_f32_16x16x32_bf16(ah[i], bh[nf], acc[mr][nf], 0, 0, 0);
                    acc[mr][nf] = __builtin_amdgcn_mfma_f32_16x16x32_bf16(al[i], bh[nf], acc[mr][nf], 0, 0, 0);
                    acc[mr][nf] = __builtin_amdgcn_mfma_f32_16x16x32_bf16(ah[i], bl[nf], acc[mr][nf], 0, 0, 0);
                }
            }
            __builtin_amdgcn_s_setprio(0);
        }
        __syncthreads();   // vmcnt(0): t+1 stage landed; all reads of buf done
    }

    // ---- epilogue: scale, block row-max, write T bf16 + mtile ----
#pragma unroll
    for (int mr = 0; mr < 8; ++mr)
#pragma unroll
        for (int nf = 0; nf < 4; ++nf) acc[mr][nf] *= 0.03125f;

#pragma unroll
    for (int mr = 0; mr < 8; ++mr)
#pragma unroll
        for (int g = 0; g < 4; ++g) {
            float m = fmaxf(fmaxf(acc[mr][0][g], acc[mr][1][g]),
                            fmaxf(acc[mr][2][g], acc[mr][3][g]));
#pragma unroll
            for (int msk = 1; msk <= 8; msk <<= 1)
                m = fmaxf(m, __shfl_xor(m, msk, 64));
            if (l15 == 0) rmax[wm * 128 + mr * 16 + lk * 4 + g][wn] = m;
        }
    __syncthreads();

#pragma unroll
    for (int mr = 0; mr < 8; ++mr)
#pragma unroll
        for (int g = 0; g < 4; ++g) {
            int r = wm * 128 + mr * 16 + lk * 4 + g;
            float4 v = *(const float4*)&rmax[r][0];
            float mt = fmaxf(fmaxf(v.x, v.y), fmaxf(v.z, v.w));
            if (wn == 0 && l15 == 0)
                mtile[(size_t)(trow0 + r) * 32 + blockIdx.x] = mt;
#pragma unroll
            for (int nf = 0; nf < 4; ++nf)
                Tb[(size_t)(trow0 + r) * 8192 + kv0 + wn * 64 + nf * 16 + l15] =
                    f2bf(acc[mr][nf][g] - mt);
        }
}

// ---------------------------------------------------------------------------
// softmax: one block per row; logits = T + mtile (stride 32); P in place.
// ---------------------------------------------------------------------------
__global__ __launch_bounds__(256) void softmax_row(unsigned short* __restrict__ Tb,
                                                   const float* __restrict__ mtile,
                                                   float* __restrict__ rinv) {
    __shared__ float red[8];
    const int r   = blockIdx.x;
    const int tid = threadIdx.x;
    const int l   = tid & 63;
    const int w   = tid >> 6;

    const float* mrow = mtile + (size_t)r * 32;
    unsigned short* trow = Tb + (size_t)r * 8192;

    bf16x8 tv[4];
    float  mt[4];
#pragma unroll
    for (int j = 0; j < 4; ++j) {
        int q = j * 256 + tid;           // 16B chunk id
        tv[j] = *(const bf16x8*)(trow + q * 8);
        mt[j] = mrow[q >> 5];            // 256 kv per tile
    }

    float lm = -3.0e38f;
#pragma unroll
    for (int j = 0; j < 4; ++j)
#pragma unroll
        for (int e = 0; e < 8; ++e)
            lm = fmaxf(lm, bf2f((unsigned short)tv[j][e]) + mt[j]);
#pragma unroll
    for (int msk = 1; msk <= 32; msk <<= 1)
        lm = fmaxf(lm, __shfl_xor(lm, msk, 64));
    if (l == 0) red[w] = lm;
    __syncthreads();
    const float m = fmaxf(fmaxf(red[0], red[1]), fmaxf(red[2], red[3]));

    float ls = 0.f;
#pragma unroll
    for (int j = 0; j < 4; ++j) {
        bf16x8 pv;
#pragma unroll
        for (int e = 0; e < 8; ++e) {
            float p = __expf(bf2f((unsigned short)tv[j][e]) + mt[j] - m);
            ls += p;
            pv[e] = (short)f2bf(p);
        }
        int q = j * 256 + tid;
        *(bf16x8*)(trow + q * 8) = pv;
    }
#pragma unroll
    for (int msk = 1; msk <= 32; msk <<= 1)
        ls += __shfl_xor(ls, msk, 64);
    if (l == 0) red[4 + w] = ls;
    __syncthreads();
    if (tid == 0)
        rinv[r] = 1.0f / (red[4] + red[5] + red[6] + red[7]);
}

// ---------------------------------------------------------------------------
// pv2: O_partial[256q x 256d] = P . X over one kv quarter (split-K 4).
// Same 2-phase dbuf gload_lds template; BK=64 kv; A=P, B=XT (single tensors).
// ---------------------------------------------------------------------------
__global__ __launch_bounds__(512, 2) void pv2(const unsigned short* __restrict__ Pb,
                                              const unsigned short* __restrict__ XT,
                                              unsigned short* __restrict__ Opart) {
    __shared__ __align__(128) char lds[131072];   // 2 x 64KB: [A 32K | B 32K]

    const int tid = threadIdx.x;
    const int l   = tid & 63;
    const int w   = tid >> 6;
    const int l15 = l & 15;
    const int lk  = l >> 4;
    const int swz = l15 & 7;
    const int wm  = w >> 2;          // q strip (128)
    const int wn  = w & 3;           // d strip (64)

    const int d0    = blockIdx.x * 256;
    const int trow0 = blockIdx.y * 256;
    const int sp    = blockIdx.z;
    const int kvb   = sp * 2048;

    // rows are 128B = 8 slots of 8 kv-cols; phys = j ^ (r&7)
    const unsigned short* src[8];
    int ldst[8];
#pragma unroll
    for (int d = 0; d < 4; ++d) {          // A = P rows
        int s = d * 512 + tid;
        int r = s >> 3, phys = s & 7;
        int j = phys ^ (r & 7);
        src[d]  = Pb + (size_t)(trow0 + r) * 8192 + kvb + j * 8;
        ldst[d] = d * 8192 + tid * 16;
    }
#pragma unroll
    for (int d = 4; d < 8; ++d) {          // B = XT rows (d features)
        int s = (d - 4) * 512 + tid;
        int r = s >> 3, phys = s & 7;
        int j = phys ^ (r & 7);
        src[d]  = XT + (size_t)(d0 + r) * 8192 + kvb + j * 8;
        ldst[d] = 32768 + (d - 4) * 8192 + tid * 16;
    }

    f32x4 acc[8][4];
#pragma unroll
    for (int mr = 0; mr < 8; ++mr)
#pragma unroll
        for (int nf = 0; nf < 4; ++nf) acc[mr][nf] = f32x4{0.f, 0.f, 0.f, 0.f};

#pragma unroll
    for (int d = 0; d < 8; ++d) dma16(src[d], &lds[ldst[d]]);
    __syncthreads();

    for (int t = 0; t < 32; ++t) {
        const int cur = t & 1;
        if (t < 32 - 1) {
            const int nb = cur ^ 1;
#pragma unroll
            for (int d = 0; d < 8; ++d)
                dma16(src[d] + (t + 1) * 64, &lds[nb * 65536 + ldst[d]]);
        }
        const char* AB = &lds[cur * 65536];

#pragma unroll
        for (int ks = 0; ks < 2; ++ks) {
            const int phys = ((ks * 4 + lk) ^ swz) << 4;
            bf16x8 xb[4];
#pragma unroll
            for (int nf = 0; nf < 4; ++nf)
                xb[nf] = *(const bf16x8*)&AB[32768 + (wn * 64 + nf * 16 + l15) * 128 + phys];
            bf16x8 pa[8];
#pragma unroll
            for (int mr = 0; mr < 8; ++mr)
                pa[mr] = *(const bf16x8*)&AB[(wm * 128 + mr * 16 + l15) * 128 + phys];
            __builtin_amdgcn_s_setprio(1);
#pragma unroll
            for (int mr = 0; mr < 8; ++mr)
#pragma unroll
                for (int nf = 0; nf < 4; ++nf)
                    acc[mr][nf] = __builtin_amdgcn_mfma_f32_16x16x32_bf16(pa[mr], xb[nf], acc[mr][nf], 0, 0, 0);
            __builtin_amdgcn_s_setprio(0);
        }
        __syncthreads();
    }

#pragma unroll
    for (int mr = 0; mr < 8; ++mr)
#pragma unroll
        for (int g = 0; g < 4; ++g) {
            int r = trow0 + wm * 128 + mr * 16 + lk * 4 + g;
#pragma unroll
            for (int nf = 0; nf < 4; ++nf)
                Opart[((size_t)sp * BAND + r) * 1024 + d0 + wn * 64 + nf * 16 + l15] =
                    f2bf(acc[mr][nf][g]);
        }
}

// ---------------------------------------------------------------------------
// combine: out = (sum of 4 kv-split partials) * rinv
// ---------------------------------------------------------------------------
__global__ __launch_bounds__(256) void combine(const unsigned short* __restrict__ Opart,
                                               const float* __restrict__ rinv,
                                               float* __restrict__ outp,
                                               int band) {
    const int r = blockIdx.x;
    const int d = threadIdx.x * 4;
    const float ri = rinv[r];
    float4 v = make_float4(0.f, 0.f, 0.f, 0.f);
#pragma unroll
    for (int s = 0; s < 4; ++s) {
        u16x4 a = *(const u16x4*)(Opart + ((size_t)s * BAND + r) * 1024 + d);
        v.x += bf2f(a.x);
        v.y += bf2f(a.y);
        v.z += bf2f(a.z);
        v.w += bf2f(a.w);
    }
    v.x *= ri; v.y *= ri; v.z *= ri; v.w *= ri;
    *(float4*)(outp + ((size_t)band * BAND + r) * 1024 + d) = v;
}

extern "C" void kernel_launch(void* const* d_in, const int* in_sizes, int n_in,
                              void* d_out, int out_size, void* d_ws, size_t ws_size,
                              hipStream_t stream) {
    const float* X  = (const float*)d_in[0];
    const float* Wq = (const float*)d_in[1];
    const float* Wk = (const float*)d_in[2];

    char* qpack = (char*)d_out;                     // [Qhi|Qlo] 4KB/row

    unsigned short* khi = (unsigned short*)d_ws;                 // 16 MiB
    unsigned short* klo = khi + (size_t)NR * DD;                 // 16 MiB
    unsigned short* xt  = klo + (size_t)NR * DD;                 // 16 MiB
    unsigned short* Tb  = xt + (size_t)DD * NR;                  // 64 MiB (T/P in place)
    float* mtile        = (float*)(Tb + (size_t)BAND * NR);      // 512 KiB
    float* rinv         = mtile + (size_t)BAND * 32;             // 16 KiB
    unsigned short* Opart = (unsigned short*)(rinv + BAND);      // 32 MiB

    dim3 pgrid(DD / 64, NR / 64);
    proj_gemm<0><<<pgrid, 256, 0, stream>>>(X, Wq, qpack, nullptr, nullptr);
    proj_gemm<1><<<pgrid, 256, 0, stream>>>(X, Wk, nullptr, khi, klo);
    prep_xt<<<dim3(NR / 64, DD / 64), 256, 0, stream>>>(X, xt);

    for (int band = 0; band < 2; ++band) {
        sgemm2<<<dim3(NR / 256, BAND / 256), 512, 0, stream>>>(qpack, khi, klo,
                                                               Tb, mtile, band);
        softmax_row<<<BAND, 256, 0, stream>>>(Tb, mtile, rinv);
        pv2<<<dim3(DD / 256, BAND / 256, 4), 512, 0, stream>>>(Tb, xt, Opart);
        combine<<<BAND, 256, 0, stream>>>(Opart, rinv, (float*)d_out, band);
    }
}

// Round 9
// 654.007 us; speedup vs baseline: 6.2025x; 1.5475x over previous
//
#include <hip/hip_runtime.h>
#include <hip/hip_bf16.h>
#include <math.h>

#define NR 8192
#define DD 1024
#define BAND 4096

typedef __attribute__((ext_vector_type(8))) short bf16x8;
typedef __attribute__((ext_vector_type(4))) float f32x4;

struct u16x4 { unsigned short x, y, z, w; };

__device__ __forceinline__ unsigned short f2bf(float v) {
    __hip_bfloat16 h = __float2bfloat16(v);
    return *(unsigned short*)&h;
}
__device__ __forceinline__ float bf2f(unsigned short u) {
    __hip_bfloat16 h = *(__hip_bfloat16*)&u;
    return __bfloat162float(h);
}

// async global->LDS: 16B/lane; LDS dest = wave-uniform base + lane*16
__device__ __forceinline__ void dma16(const void* g, void* l) {
    __builtin_amdgcn_global_load_lds(
        (const __attribute__((address_space(1))) unsigned int*)g,
        (__attribute__((address_space(3))) unsigned int*)l, 16, 0, 0);
}

// ---------------------------------------------------------------------------
// prep_xsplit: X fp32 -> xpack rows [hi 2048B | lo 2048B] (qpack format)
// ---------------------------------------------------------------------------
__global__ __launch_bounds__(256) void prep_xsplit(const float* __restrict__ X,
                                                   char* __restrict__ xpack) {
    const int idx  = blockIdx.x * 256 + threadIdx.x;
    const int base = idx * 4;
    const int r = base >> 10;
    const int c = base & 1023;
    float4 v = *(const float4*)(X + (size_t)base);
    u16x4 hi, lo;
    hi.x = f2bf(v.x); lo.x = f2bf(v.x - bf2f(hi.x));
    hi.y = f2bf(v.y); lo.y = f2bf(v.y - bf2f(hi.y));
    hi.z = f2bf(v.z); lo.z = f2bf(v.z - bf2f(hi.z));
    hi.w = f2bf(v.w); lo.w = f2bf(v.w - bf2f(hi.w));
    *(u16x4*)(xpack + (size_t)r * 4096 + c * 2)        = hi;
    *(u16x4*)(xpack + (size_t)r * 4096 + 2048 + c * 2) = lo;
}

// ---------------------------------------------------------------------------
// prep_wt: W[k][n] fp32 -> WT hi/lo bf16 [n][k]  (B-operand layout for proj)
// ---------------------------------------------------------------------------
__global__ __launch_bounds__(256) void prep_wt(const float* __restrict__ W,
                                               unsigned short* __restrict__ WThi,
                                               unsigned short* __restrict__ WTlo) {
    __shared__ float t[64][65];
    const int k0 = blockIdx.x * 64;
    const int n0 = blockIdx.y * 64;
    const int tid = threadIdx.x;
    const int tr = tid >> 6;
    const int tc = tid & 63;
#pragma unroll
    for (int rep = 0; rep < 16; ++rep) {
        int r = rep * 4 + tr;
        t[r][tc] = W[(size_t)(k0 + r) * DD + n0 + tc];
    }
    __syncthreads();
#pragma unroll
    for (int rep = 0; rep < 16; ++rep) {
        int c = rep * 4 + tr;                 // n within tile
        float v = t[tc][c];
        unsigned short hi = f2bf(v);
        WThi[(size_t)(n0 + c) * DD + k0 + tc] = hi;
        WTlo[(size_t)(n0 + c) * DD + k0 + tc] = f2bf(v - bf2f(hi));
    }
}

// ---------------------------------------------------------------------------
// X^T bf16: XT[1024][8192] (PV B-operand layout)
// ---------------------------------------------------------------------------
__global__ __launch_bounds__(256) void prep_xt(const float* __restrict__ X,
                                               unsigned short* __restrict__ XT) {
    __shared__ float t[64][65];
    const int r0 = blockIdx.x * 64;
    const int c0 = blockIdx.y * 64;
    const int tid = threadIdx.x;
    const int tr = tid >> 6;
    const int tc = tid & 63;
#pragma unroll
    for (int rep = 0; rep < 16; ++rep) {
        int r = rep * 4 + tr;
        t[r][tc] = X[(size_t)(r0 + r) * DD + c0 + tc];
    }
    __syncthreads();
#pragma unroll
    for (int rep = 0; rep < 16; ++rep) {
        int c = rep * 4 + tr;
        XT[(size_t)(c0 + c) * NR + r0 + tc] = f2bf(t[tc][c]);
    }
}

// ---------------------------------------------------------------------------
// proj_mfma: C[128m x 256n] = X.W via 3-product split-bf16 MFMA.
// Same 2-phase dbuf gload_lds template as sgemm2. BK=32.
// MODE 0: epilogue packs [hi|lo] per-row records into qpack (d_out).
// MODE 1: epilogue writes khi/klo arrays.
// ---------------------------------------------------------------------------
template <int MODE>
__global__ __launch_bounds__(512, 2) void proj_mfma(
        const char* __restrict__ xpk,
        const unsigned short* __restrict__ WThi,
        const unsigned short* __restrict__ WTlo,
        char* __restrict__ qpack,
        unsigned short* __restrict__ khi,
        unsigned short* __restrict__ klo) {
    __shared__ __align__(128) char lds[98304];   // 2 x 48KB: [A 16K | B 32K]

    const int tid = threadIdx.x;
    const int l   = tid & 63;
    const int w   = tid >> 6;
    const int l15 = l & 15;
    const int lk  = l >> 4;
    const int swz = l15 & 7;
    const int wm  = w >> 2;          // 0..1  m strip (64)
    const int wn  = w & 3;           // 0..3  n strip (64)

    const int n0 = blockIdx.x * 256;
    const int m0 = blockIdx.y * 128;

    // ---- DMA maps: 6 instr/thread/K-step; src advances 64B per t ----
    const char* src[6];
    int ldst[6];
#pragma unroll
    for (int d = 0; d < 2; ++d) {          // A = X rows (hi|lo packed)
        int s = d * 512 + tid;
        int r = s >> 3, phys = s & 7;
        int j = phys ^ (r & 7);
        src[d]  = xpk + (size_t)(m0 + r) * 4096 + (j >> 2) * 2048 + (j & 3) * 16;
        ldst[d] = d * 8192 + tid * 16;
    }
#pragma unroll
    for (int d = 2; d < 6; ++d) {          // B = WT rows (hi/lo arrays)
        int s = (d - 2) * 512 + tid;
        int r = s >> 3, phys = s & 7;
        int j = phys ^ (r & 7);
        const unsigned short* base = (j >> 2) ? WTlo : WThi;
        src[d]  = (const char*)(base + (size_t)(n0 + r) * DD + (j & 3) * 8);
        ldst[d] = 16384 + (d - 2) * 8192 + tid * 16;
    }

    f32x4 acc[4][4];
#pragma unroll
    for (int mr = 0; mr < 4; ++mr)
#pragma unroll
        for (int nf = 0; nf < 4; ++nf) acc[mr][nf] = f32x4{0.f, 0.f, 0.f, 0.f};

#pragma unroll
    for (int d = 0; d < 6; ++d) dma16(src[d], &lds[ldst[d]]);
    __syncthreads();

    for (int t = 0; t < 32; ++t) {
        const int cur = t & 1;
        if (t < 31) {
            const int nb = cur ^ 1;
#pragma unroll
            for (int d = 0; d < 6; ++d)
                dma16(src[d] + (t + 1) * 64, &lds[nb * 49152 + ldst[d]]);
        }
        const char* AB = &lds[cur * 49152];

        bf16x8 bh[4], bl[4];
#pragma unroll
        for (int nf = 0; nf < 4; ++nf) {
            int row = wn * 64 + nf * 16 + l15;
            bh[nf] = *(const bf16x8*)&AB[16384 + row * 128 + ((lk ^ swz) << 4)];
            bl[nf] = *(const bf16x8*)&AB[16384 + row * 128 + (((lk ^ 4) ^ swz) << 4)];
        }
        bf16x8 ah[4], al[4];
#pragma unroll
        for (int i = 0; i < 4; ++i) {
            int row = wm * 64 + i * 16 + l15;
            ah[i] = *(const bf16x8*)&AB[row * 128 + ((lk ^ swz) << 4)];
            al[i] = *(const bf16x8*)&AB[row * 128 + (((lk ^ 4) ^ swz) << 4)];
        }
        __builtin_amdgcn_s_setprio(1);
#pragma unroll
        for (int mr = 0; mr < 4; ++mr)
#pragma unroll
            for (int nf = 0; nf < 4; ++nf) {
                acc[mr][nf] = __builtin_amdgcn_mfma_f32_16x16x32_bf16(ah[mr], bh[nf], acc[mr][nf], 0, 0, 0);
                acc[mr][nf] = __builtin_amdgcn_mfma_f32_16x16x32_bf16(al[mr], bh[nf], acc[mr][nf], 0, 0, 0);
                acc[mr][nf] = __builtin_amdgcn_mfma_f32_16x16x32_bf16(ah[mr], bl[nf], acc[mr][nf], 0, 0, 0);
            }
        __builtin_amdgcn_s_setprio(0);
        __syncthreads();
    }

    // ---- epilogue: split hi/lo, write records ----
#pragma unroll
    for (int mr = 0; mr < 4; ++mr)
#pragma unroll
        for (int g = 0; g < 4; ++g) {
            int row = m0 + wm * 64 + mr * 16 + lk * 4 + g;
#pragma unroll
            for (int nf = 0; nf < 4; ++nf) {
                int col = n0 + wn * 64 + nf * 16 + l15;
                float v = acc[mr][nf][g];
                unsigned short hi = f2bf(v);
                unsigned short lo = f2bf(v - bf2f(hi));
                if (MODE == 0) {
                    *(unsigned short*)(qpack + (size_t)row * 4096 + col * 2)        = hi;
                    *(unsigned short*)(qpack + (size_t)row * 4096 + 2048 + col * 2) = lo;
                } else {
                    khi[(size_t)row * DD + col] = hi;
                    klo[(size_t)row * DD + col] = lo;
                }
            }
        }
}

// ---------------------------------------------------------------------------
// sgemm2: T[256q x 256kv] = Q.K^T * scale - tilemax, bf16 out.  (proven R8)
// ---------------------------------------------------------------------------
__global__ __launch_bounds__(512, 2) void sgemm2(const char* __restrict__ qpk,
                                                 const unsigned short* __restrict__ Khi,
                                                 const unsigned short* __restrict__ Klo,
                                                 unsigned short* __restrict__ Tb,
                                                 float* __restrict__ mtile,
                                                 int band) {
    __shared__ __align__(128) char lds[131072];   // 2 x 64KB: [A 32K | B 32K]
    __shared__ float rmax[256][4];

    const int tid = threadIdx.x;
    const int l   = tid & 63;
    const int w   = tid >> 6;
    const int l15 = l & 15;
    const int lk  = l >> 4;
    const int swz = l15 & 7;
    const int wm  = w >> 2;
    const int wn  = w & 3;

    const int kv0   = blockIdx.x * 256;
    const int trow0 = blockIdx.y * 256;
    const size_t qrow0 = (size_t)band * BAND + trow0;

    const char* src[8];
    int ldst[8];
#pragma unroll
    for (int d = 0; d < 4; ++d) {
        int s = d * 512 + tid;
        int r = s >> 3, phys = s & 7;
        int j = phys ^ (r & 7);
        src[d]  = qpk + (qrow0 + r) * 4096 + (j >> 2) * 2048 + (j & 3) * 16;
        ldst[d] = d * 8192 + tid * 16;
    }
#pragma unroll
    for (int d = 4; d < 8; ++d) {
        int s = (d - 4) * 512 + tid;
        int r = s >> 3, phys = s & 7;
        int j = phys ^ (r & 7);
        const unsigned short* base = (j >> 2) ? Klo : Khi;
        src[d]  = (const char*)(base + (size_t)(kv0 + r) * 1024 + (j & 3) * 8);
        ldst[d] = 32768 + (d - 4) * 8192 + tid * 16;
    }

    f32x4 acc[8][4];
#pragma unroll
    for (int mr = 0; mr < 8; ++mr)
#pragma unroll
        for (int nf = 0; nf < 4; ++nf) acc[mr][nf] = f32x4{0.f, 0.f, 0.f, 0.f};

#pragma unroll
    for (int d = 0; d < 8; ++d) dma16(src[d], &lds[ldst[d]]);
    __syncthreads();

    for (int t = 0; t < 32; ++t) {
        const int cur = t & 1;
        if (t < 32 - 1) {
            const int nb = cur ^ 1;
#pragma unroll
            for (int d = 0; d < 8; ++d)
                dma16(src[d] + (t + 1) * 64, &lds[nb * 65536 + ldst[d]]);
        }
        const char* AB = &lds[cur * 65536];

        bf16x8 bh[4], bl[4];
#pragma unroll
        for (int nf = 0; nf < 4; ++nf) {
            int row = wn * 64 + nf * 16 + l15;
            bh[nf] = *(const bf16x8*)&AB[32768 + row * 128 + ((lk ^ swz) << 4)];
            bl[nf] = *(const bf16x8*)&AB[32768 + row * 128 + (((lk ^ 4) ^ swz) << 4)];
        }
#pragma unroll
        for (int half = 0; half < 2; ++half) {
            bf16x8 ah[4], al[4];
#pragma unroll
            for (int i = 0; i < 4; ++i) {
                int row = wm * 128 + (half * 4 + i) * 16 + l15;
                ah[i] = *(const bf16x8*)&AB[row * 128 + ((lk ^ swz) << 4)];
                al[i] = *(const bf16x8*)&AB[row * 128 + (((lk ^ 4) ^ swz) << 4)];
            }
            __builtin_amdgcn_s_setprio(1);
#pragma unroll
            for (int i = 0; i < 4; ++i) {
                int mr = half * 4 + i;
#pragma unroll
                for (int nf = 0; nf < 4; ++nf) {
                    acc[mr][nf] = __builtin_amdgcn_mfma_f32_16x16x32_bf16(ah[i], bh[nf], acc[mr][nf], 0, 0, 0);
                    acc[mr][nf] = __builtin_amdgcn_mfma_f32_16x16x32_bf16(al[i], bh[nf], acc[mr][nf], 0, 0, 0);
                    acc[mr][nf] = __builtin_amdgcn_mfma_f32_16x16x32_bf16(ah[i], bl[nf], acc[mr][nf], 0, 0, 0);
                }
            }
            __builtin_amdgcn_s_setprio(0);
        }
        __syncthreads();
    }

#pragma unroll
    for (int mr = 0; mr < 8; ++mr)
#pragma unroll
        for (int nf = 0; nf < 4; ++nf) acc[mr][nf] *= 0.03125f;

#pragma unroll
    for (int mr = 0; mr < 8; ++mr)
#pragma unroll
        for (int g = 0; g < 4; ++g) {
            float m = fmaxf(fmaxf(acc[mr][0][g], acc[mr][1][g]),
                            fmaxf(acc[mr][2][g], acc[mr][3][g]));
#pragma unroll
            for (int msk = 1; msk <= 8; msk <<= 1)
                m = fmaxf(m, __shfl_xor(m, msk, 64));
            if (l15 == 0) rmax[wm * 128 + mr * 16 + lk * 4 + g][wn] = m;
        }
    __syncthreads();

#pragma unroll
    for (int mr = 0; mr < 8; ++mr)
#pragma unroll
        for (int g = 0; g < 4; ++g) {
            int r = wm * 128 + mr * 16 + lk * 4 + g;
            float4 v = *(const float4*)&rmax[r][0];
            float mt = fmaxf(fmaxf(v.x, v.y), fmaxf(v.z, v.w));
            if (wn == 0 && l15 == 0)
                mtile[(size_t)(trow0 + r) * 32 + blockIdx.x] = mt;
#pragma unroll
            for (int nf = 0; nf < 4; ++nf)
                Tb[(size_t)(trow0 + r) * 8192 + kv0 + wn * 64 + nf * 16 + l15] =
                    f2bf(acc[mr][nf][g] - mt);
        }
}

// ---------------------------------------------------------------------------
// softmax: one block per row; logits = T + mtile (stride 32); P in place.
// ---------------------------------------------------------------------------
__global__ __launch_bounds__(256) void softmax_row(unsigned short* __restrict__ Tb,
                                                   const float* __restrict__ mtile,
                                                   float* __restrict__ rinv) {
    __shared__ float red[8];
    const int r   = blockIdx.x;
    const int tid = threadIdx.x;
    const int l   = tid & 63;
    const int w   = tid >> 6;

    const float* mrow = mtile + (size_t)r * 32;
    unsigned short* trow = Tb + (size_t)r * 8192;

    bf16x8 tv[4];
    float  mt[4];
#pragma unroll
    for (int j = 0; j < 4; ++j) {
        int q = j * 256 + tid;
        tv[j] = *(const bf16x8*)(trow + q * 8);
        mt[j] = mrow[q >> 5];
    }

    float lm = -3.0e38f;
#pragma unroll
    for (int j = 0; j < 4; ++j)
#pragma unroll
        for (int e = 0; e < 8; ++e)
            lm = fmaxf(lm, bf2f((unsigned short)tv[j][e]) + mt[j]);
#pragma unroll
    for (int msk = 1; msk <= 32; msk <<= 1)
        lm = fmaxf(lm, __shfl_xor(lm, msk, 64));
    if (l == 0) red[w] = lm;
    __syncthreads();
    const float m = fmaxf(fmaxf(red[0], red[1]), fmaxf(red[2], red[3]));

    float ls = 0.f;
#pragma unroll
    for (int j = 0; j < 4; ++j) {
        bf16x8 pv;
#pragma unroll
        for (int e = 0; e < 8; ++e) {
            float p = __expf(bf2f((unsigned short)tv[j][e]) + mt[j] - m);
            ls += p;
            pv[e] = (short)f2bf(p);
        }
        int q = j * 256 + tid;
        *(bf16x8*)(trow + q * 8) = pv;
    }
#pragma unroll
    for (int msk = 1; msk <= 32; msk <<= 1)
        ls += __shfl_xor(ls, msk, 64);
    if (l == 0) red[4 + w] = ls;
    __syncthreads();
    if (tid == 0)
        rinv[r] = 1.0f / (red[4] + red[5] + red[6] + red[7]);
}

// ---------------------------------------------------------------------------
// pv2: O_partial[256q x 256d] = P . X over one kv quarter (split-K 4).
// ---------------------------------------------------------------------------
__global__ __launch_bounds__(512, 2) void pv2(const unsigned short* __restrict__ Pb,
                                              const unsigned short* __restrict__ XT,
                                              unsigned short* __restrict__ Opart) {
    __shared__ __align__(128) char lds[131072];

    const int tid = threadIdx.x;
    const int l   = tid & 63;
    const int w   = tid >> 6;
    const int l15 = l & 15;
    const int lk  = l >> 4;
    const int swz = l15 & 7;
    const int wm  = w >> 2;
    const int wn  = w & 3;

    const int d0    = blockIdx.x * 256;
    const int trow0 = blockIdx.y * 256;
    const int sp    = blockIdx.z;
    const int kvb   = sp * 2048;

    const unsigned short* src[8];
    int ldst[8];
#pragma unroll
    for (int d = 0; d < 4; ++d) {
        int s = d * 512 + tid;
        int r = s >> 3, phys = s & 7;
        int j = phys ^ (r & 7);
        src[d]  = Pb + (size_t)(trow0 + r) * 8192 + kvb + j * 8;
        ldst[d] = d * 8192 + tid * 16;
    }
#pragma unroll
    for (int d = 4; d < 8; ++d) {
        int s = (d - 4) * 512 + tid;
        int r = s >> 3, phys = s & 7;
        int j = phys ^ (r & 7);
        src[d]  = XT + (size_t)(d0 + r) * 8192 + kvb + j * 8;
        ldst[d] = 32768 + (d - 4) * 8192 + tid * 16;
    }

    f32x4 acc[8][4];
#pragma unroll
    for (int mr = 0; mr < 8; ++mr)
#pragma unroll
        for (int nf = 0; nf < 4; ++nf) acc[mr][nf] = f32x4{0.f, 0.f, 0.f, 0.f};

#pragma unroll
    for (int d = 0; d < 8; ++d) dma16(src[d], &lds[ldst[d]]);
    __syncthreads();

    for (int t = 0; t < 32; ++t) {
        const int cur = t & 1;
        if (t < 32 - 1) {
            const int nb = cur ^ 1;
#pragma unroll
            for (int d = 0; d < 8; ++d)
                dma16(src[d] + (t + 1) * 64, &lds[nb * 65536 + ldst[d]]);
        }
        const char* AB = &lds[cur * 65536];

#pragma unroll
        for (int ks = 0; ks < 2; ++ks) {
            const int phys = ((ks * 4 + lk) ^ swz) << 4;
            bf16x8 xb[4];
#pragma unroll
            for (int nf = 0; nf < 4; ++nf)
                xb[nf] = *(const bf16x8*)&AB[32768 + (wn * 64 + nf * 16 + l15) * 128 + phys];
            bf16x8 pa[8];
#pragma unroll
            for (int mr = 0; mr < 8; ++mr)
                pa[mr] = *(const bf16x8*)&AB[(wm * 128 + mr * 16 + l15) * 128 + phys];
            __builtin_amdgcn_s_setprio(1);
#pragma unroll
            for (int mr = 0; mr < 8; ++mr)
#pragma unroll
                for (int nf = 0; nf < 4; ++nf)
                    acc[mr][nf] = __builtin_amdgcn_mfma_f32_16x16x32_bf16(pa[mr], xb[nf], acc[mr][nf], 0, 0, 0);
            __builtin_amdgcn_s_setprio(0);
        }
        __syncthreads();
    }

#pragma unroll
    for (int mr = 0; mr < 8; ++mr)
#pragma unroll
        for (int g = 0; g < 4; ++g) {
            int r = trow0 + wm * 128 + mr * 16 + lk * 4 + g;
#pragma unroll
            for (int nf = 0; nf < 4; ++nf)
                Opart[((size_t)sp * BAND + r) * 1024 + d0 + wn * 64 + nf * 16 + l15] =
                    f2bf(acc[mr][nf][g]);
        }
}

// ---------------------------------------------------------------------------
// combine: out = (sum of 4 kv-split partials) * rinv
// ---------------------------------------------------------------------------
__global__ __launch_bounds__(256) void combine(const unsigned short* __restrict__ Opart,
                                               const float* __restrict__ rinv,
                                               float* __restrict__ outp,
                                               int band) {
    const int r = blockIdx.x;
    const int d = threadIdx.x * 4;
    const float ri = rinv[r];
    float4 v = make_float4(0.f, 0.f, 0.f, 0.f);
#pragma unroll
    for (int s = 0; s < 4; ++s) {
        u16x4 a = *(const u16x4*)(Opart + ((size_t)s * BAND + r) * 1024 + d);
        v.x += bf2f(a.x);
        v.y += bf2f(a.y);
        v.z += bf2f(a.z);
        v.w += bf2f(a.w);
    }
    v.x *= ri; v.y *= ri; v.z *= ri; v.w *= ri;
    *(float4*)(outp + ((size_t)band * BAND + r) * 1024 + d) = v;
}

extern "C" void kernel_launch(void* const* d_in, const int* in_sizes, int n_in,
                              void* d_out, int out_size, void* d_ws, size_t ws_size,
                              hipStream_t stream) {
    const float* X  = (const float*)d_in[0];
    const float* Wq = (const float*)d_in[1];
    const float* Wk = (const float*)d_in[2];

    char* qpack = (char*)d_out;                     // [Qhi|Qlo] 4KB/row

    unsigned short* khi = (unsigned short*)d_ws;                 // 16 MiB
    unsigned short* klo = khi + (size_t)NR * DD;                 // 16 MiB
    unsigned short* xt  = klo + (size_t)NR * DD;                 // 16 MiB
    unsigned short* Tb  = xt + (size_t)DD * NR;                  // 64 MiB (T/P in place)
    float* mtile        = (float*)(Tb + (size_t)BAND * NR);      // 512 KiB
    float* rinv         = mtile + (size_t)BAND * 32;             // 16 KiB
    unsigned short* Opart = (unsigned short*)(rinv + BAND);      // 32 MiB

    // phase-disjoint aliases (no extra workspace):
    // xpack (32 MiB) lives in Opart's region — dead before pv2 writes it.
    // WT hi/lo (4 x 2 MiB) live at the head of Tb — dead before sgemm2 writes Tb.
    char* xpack = (char*)Opart;
    unsigned short* wtq_hi = Tb;
    unsigned short* wtq_lo = Tb + (size_t)DD * DD;
    unsigned short* wtk_hi = Tb + (size_t)2 * DD * DD;
    unsigned short* wtk_lo = Tb + (size_t)3 * DD * DD;

    prep_xsplit<<<NR * DD / 4 / 256, 256, 0, stream>>>(X, xpack);
    prep_wt<<<dim3(16, 16), 256, 0, stream>>>(Wq, wtq_hi, wtq_lo);
    prep_wt<<<dim3(16, 16), 256, 0, stream>>>(Wk, wtk_hi, wtk_lo);
    prep_xt<<<dim3(NR / 64, DD / 64), 256, 0, stream>>>(X, xt);

    proj_mfma<0><<<dim3(DD / 256, NR / 128), 512, 0, stream>>>(
        xpack, wtq_hi, wtq_lo, qpack, nullptr, nullptr);
    proj_mfma<1><<<dim3(DD / 256, NR / 128), 512, 0, stream>>>(
        xpack, wtk_hi, wtk_lo, nullptr, khi, klo);

    for (int band = 0; band < 2; ++band) {
        sgemm2<<<dim3(NR / 256, BAND / 256), 512, 0, stream>>>(qpack, khi, klo,
                                                               Tb, mtile, band);
        softmax_row<<<BAND, 256, 0, stream>>>(Tb, mtile, rinv);
        pv2<<<dim3(DD / 256, BAND / 256, 4), 512, 0, stream>>>(Tb, xt, Opart);
        combine<<<BAND, 256, 0, stream>>>(Opart, rinv, (float*)d_out, band);
    }
}